// Round 1
// baseline (1215.421 us; speedup 1.0000x reference)
//
#include <hip/hip_runtime.h>
#include <cstddef>

#define HEADS 4

// ---------------- CSR build ----------------

__global__ void zero_int_kernel(int* __restrict__ p, int n) {
    int i = blockIdx.x * blockDim.x + threadIdx.x;
    if (i < n) p[i] = 0;
}

__global__ void count_edges_kernel(const int* __restrict__ ei, int E, int N,
                                   int* __restrict__ cnt) {
    int e = blockIdx.x * blockDim.x + threadIdx.x;
    if (e >= E + N) return;
    int d = (e < E) ? ei[E + e] : (e - E);  // self loops appended
    atomicAdd(&cnt[d], 1);
}

__global__ void scan_kernel(const int* __restrict__ cnt, int* __restrict__ rp, int n) {
    __shared__ int sh[1024];
    int t = threadIdx.x;
    int run = 0;
    if (t == 0) rp[0] = 0;
    for (int base = 0; base < n; base += 1024) {
        int v = (base + t < n) ? cnt[base + t] : 0;
        sh[t] = v;
        __syncthreads();
        for (int off = 1; off < 1024; off <<= 1) {
            int add = (t >= off) ? sh[t - off] : 0;
            __syncthreads();
            sh[t] += add;
            __syncthreads();
        }
        if (base + t < n) rp[base + t + 1] = run + sh[t];
        run += sh[1023];
        __syncthreads();
    }
}

__global__ void scatter_edges_kernel(const int* __restrict__ ei, int E, int N,
                                     const int* __restrict__ rp, int* __restrict__ cur,
                                     int* __restrict__ csrc) {
    int e = blockIdx.x * blockDim.x + threadIdx.x;
    if (e >= E + N) return;
    int s, d;
    if (e < E) { s = ei[e]; d = ei[E + e]; } else { s = e - E; d = s; }
    int pos = rp[d] + atomicAdd(&cur[d], 1);
    csrc[pos] = s;
}

// ---------------- f32 GEMM: C[M,Nc] = A[M,K] @ B[K,Nc] ----------------
// 64x64 tile, 256 threads, 4x4 per thread. K % 16 == 0, Nc % 64 == 0.

__global__ __launch_bounds__(256) void gemm_f32_kernel(
    const float* __restrict__ A, const float* __restrict__ B,
    float* __restrict__ C, int M, int K, int Nc) {
    __shared__ float As[16][68];  // [k][m], padded
    __shared__ float Bs[16][68];  // [k][n], padded (row stride 272B, 16B-aligned)
    int tid = threadIdx.x;
    int bm = blockIdx.y * 64;
    int bn = blockIdx.x * 64;
    int tx = tid & 15;   // n-group
    int ty = tid >> 4;   // m-group
    float acc[4][4] = {};
    for (int k0 = 0; k0 < K; k0 += 16) {
        {   // A tile: 64(m) x 16(k)
            int row = tid >> 2;
            int kk = (tid & 3) * 4;
            int m = bm + row;
            float4 v = make_float4(0.f, 0.f, 0.f, 0.f);
            if (m < M) v = *(const float4*)(A + (size_t)m * K + k0 + kk);
            As[kk + 0][row] = v.x; As[kk + 1][row] = v.y;
            As[kk + 2][row] = v.z; As[kk + 3][row] = v.w;
        }
        {   // B tile: 16(k) x 64(n)
            int krow = tid >> 4;
            int nn = (tid & 15) * 4;
            float4 v = *(const float4*)(B + (size_t)(k0 + krow) * Nc + bn + nn);
            *(float4*)&Bs[krow][nn] = v;
        }
        __syncthreads();
#pragma unroll
        for (int k = 0; k < 16; k++) {
            float a[4], b[4];
#pragma unroll
            for (int i = 0; i < 4; i++) a[i] = As[k][ty * 4 + i];
#pragma unroll
            for (int j = 0; j < 4; j++) b[j] = Bs[k][tx * 4 + j];
#pragma unroll
            for (int i = 0; i < 4; i++)
#pragma unroll
                for (int j = 0; j < 4; j++) acc[i][j] += a[i] * b[j];
        }
        __syncthreads();
    }
#pragma unroll
    for (int i = 0; i < 4; i++) {
        int m = bm + ty * 4 + i;
        if (m < M) {
            float4 v = make_float4(acc[i][0], acc[i][1], acc[i][2], acc[i][3]);
            *(float4*)(C + (size_t)m * Nc + bn + tx * 4) = v;
        }
    }
}

// ---------------- attention logits: al[n,h] = sum_c h[n,h,c]*a[h,c] ----------------
// one wave per (n, head)

__global__ __launch_bounds__(256) void al_kernel(
    const float* __restrict__ h, const float* __restrict__ a_src,
    const float* __restrict__ a_dst, float* __restrict__ al_s,
    float* __restrict__ al_d, int NH, int HC, int C) {
    int wid = blockIdx.x * 4 + (threadIdx.x >> 6);
    int lane = threadIdx.x & 63;
    if (wid >= NH) return;
    int n = wid >> 2;
    int hh = wid & 3;
    const float* row = h + (size_t)n * HC + hh * C;
    float s1 = 0.f, s2 = 0.f;
    for (int c = lane; c < C; c += 64) {
        float v = row[c];
        s1 += v * a_src[hh * C + c];
        s2 += v * a_dst[hh * C + c];
    }
#pragma unroll
    for (int off = 32; off > 0; off >>= 1) {
        s1 += __shfl_down(s1, off);
        s2 += __shfl_down(s2, off);
    }
    if (lane == 0) { al_s[wid] = s1; al_d[wid] = s2; }
}

// ---------------- segment softmax stats (max + expsum), thread per (dst,head) ----------------

__global__ void stats_kernel(const int* __restrict__ rp, const int* __restrict__ csrc,
                             const float* __restrict__ al_s, const float* __restrict__ al_d,
                             float* __restrict__ mmax, float* __restrict__ denom, int NH) {
    int t = blockIdx.x * blockDim.x + threadIdx.x;
    if (t >= NH) return;
    int n = t >> 2;
    int hh = t & 3;
    int beg = rp[n], end = rp[n + 1];
    float ad = al_d[t];
    float m = -3.402823466e38f;
    for (int e = beg; e < end; ++e) {
        float v = al_s[csrc[e] * HEADS + hh] + ad;
        v = v > 0.f ? v : 0.2f * v;
        m = fmaxf(m, v);
    }
    float sum = 0.f;
    for (int e = beg; e < end; ++e) {
        float v = al_s[csrc[e] * HEADS + hh] + ad;
        v = v > 0.f ? v : 0.2f * v;
        sum += __expf(v - m);
    }
    mmax[t] = m;
    denom[t] = sum;
}

// ---------------- aggregate: block per dst node ----------------

__global__ __launch_bounds__(256) void agg_kernel(
    const int* __restrict__ rp, const int* __restrict__ csrc,
    const float* __restrict__ h, const float* __restrict__ al_s,
    const float* __restrict__ al_d, const float* __restrict__ mmax,
    const float* __restrict__ denom, const float* __restrict__ bias,
    float* __restrict__ out, int HC, int C, int do_mean, int do_relu) {
    __shared__ float sh[512];
    int n = blockIdx.x;
    int tid = threadIdx.x;
    int beg = rp[n], end = rp[n + 1];
    int ch0 = tid, ch1 = tid + 256;
    bool a0 = ch0 < HC, a1 = ch1 < HC;
    int h0 = a0 ? ch0 / C : 0;
    int h1 = a1 ? ch1 / C : 0;
    float ad0 = al_d[n * HEADS + h0], m0 = mmax[n * HEADS + h0];
    float r0 = 1.0f / (denom[n * HEADS + h0] + 1e-16f);
    float ad1 = al_d[n * HEADS + h1], m1 = mmax[n * HEADS + h1];
    float r1 = 1.0f / (denom[n * HEADS + h1] + 1e-16f);
    float acc0 = 0.f, acc1 = 0.f;
    for (int e = beg; e < end; ++e) {
        int s = csrc[e];
        const float* row = h + (size_t)s * HC;
        float v0 = al_s[s * HEADS + h0] + ad0;
        v0 = v0 > 0.f ? v0 : 0.2f * v0;
        float alpha0 = __expf(v0 - m0) * r0;
        if (a0) acc0 += alpha0 * row[ch0];
        if (a1) {
            float v1 = al_s[s * HEADS + h1] + ad1;
            v1 = v1 > 0.f ? v1 : 0.2f * v1;
            float alpha1 = __expf(v1 - m1) * r1;
            acc1 += alpha1 * row[ch1];
        }
    }
    if (!do_mean) {
        if (a0) {
            float v = acc0 + bias[ch0];
            if (do_relu) v = fmaxf(v, 0.f);
            out[(size_t)n * HC + ch0] = v;
        }
        if (a1) {
            float v = acc1 + bias[ch1];
            if (do_relu) v = fmaxf(v, 0.f);
            out[(size_t)n * HC + ch1] = v;
        }
    } else {
        if (a0) sh[ch0] = acc0;
        if (a1) sh[ch1] = acc1;
        __syncthreads();
        if (tid < C) {
            float v = (sh[tid] + sh[C + tid] + sh[2 * C + tid] + sh[3 * C + tid]) * 0.25f
                      + bias[tid];
            out[(size_t)n * C + tid] = v;
        }
    }
}

// ---------------- orchestration ----------------

extern "C" void kernel_launch(void* const* d_in, const int* in_sizes, int n_in,
                              void* d_out, int out_size, void* d_ws, size_t ws_size,
                              hipStream_t stream) {
    (void)n_in; (void)out_size; (void)ws_size;
    const float* x   = (const float*)d_in[0];
    const int*   ei  = (const int*)d_in[1];
    const float* W1  = (const float*)d_in[2];
    const float* as1 = (const float*)d_in[3];
    const float* ad1 = (const float*)d_in[4];
    const float* b1  = (const float*)d_in[5];
    const float* W2  = (const float*)d_in[6];
    const float* as2 = (const float*)d_in[7];
    const float* ad2 = (const float*)d_in[8];
    const float* b2  = (const float*)d_in[9];
    const float* Wm  = (const float*)d_in[10];
    const float* a_sm = (const float*)d_in[11];
    const float* a_dm = (const float*)d_in[12];
    const float* bm  = (const float*)d_in[13];
    const float* Wl  = (const float*)d_in[14];
    const float* a_sl = (const float*)d_in[15];
    const float* a_dl = (const float*)d_in[16];
    const float* bl  = (const float*)d_in[17];
    float* outp = (float*)d_out;

    const int N  = in_sizes[0] / 256;   // 30000
    const int E  = in_sizes[1] / 2;     // 480000
    const int ET = E + N;               // with self loops
    const int NH = N * HEADS;

    // workspace carve-up (all 256B-aligned)
    auto align_up = [](size_t v) { return (v + 255) & ~(size_t)255; };
    char* w = (char*)d_ws;
    int* row_ptr = (int*)w;  w += align_up((size_t)(N + 1) * 4);
    int* cnt     = (int*)w;  w += align_up((size_t)N * 4);
    int* csrc    = (int*)w;  w += align_up((size_t)ET * 4);
    float* al_s  = (float*)w; w += align_up((size_t)NH * 4);
    float* al_d  = (float*)w; w += align_up((size_t)NH * 4);
    float* mmax  = (float*)w; w += align_up((size_t)NH * 4);
    float* denom = (float*)w; w += align_up((size_t)NH * 4);
    float* bufH  = (float*)w; w += align_up((size_t)N * 512 * 4);
    float* bufO  = (float*)w; w += align_up((size_t)N * 512 * 4);

    // ---- CSR build (graph identical for all 4 layers) ----
    int gzN = (N + 255) / 256;
    int gzE = (ET + 255) / 256;
    zero_int_kernel<<<gzN, 256, 0, stream>>>(cnt, N);
    count_edges_kernel<<<gzE, 256, 0, stream>>>(ei, E, N, cnt);
    scan_kernel<<<1, 1024, 0, stream>>>(cnt, row_ptr, N);
    zero_int_kernel<<<gzN, 256, 0, stream>>>(cnt, N);
    scatter_edges_kernel<<<gzE, 256, 0, stream>>>(ei, E, N, row_ptr, cnt, csrc);

    int gM = (N + 63) / 64;
    int gNH = (NH + 255) / 256;
    int gAL = (NH + 3) / 4;

    // ---- Layer 1: GAT(256 -> 4x64, concat) + ReLU ----
    gemm_f32_kernel<<<dim3(256 / 64, gM), 256, 0, stream>>>(x, W1, bufH, N, 256, 256);
    al_kernel<<<gAL, 256, 0, stream>>>(bufH, as1, ad1, al_s, al_d, NH, 256, 64);
    stats_kernel<<<gNH, 256, 0, stream>>>(row_ptr, csrc, al_s, al_d, mmax, denom, NH);
    agg_kernel<<<N, 256, 0, stream>>>(row_ptr, csrc, bufH, al_s, al_d, mmax, denom,
                                      b1, bufO, 256, 64, 0, 1);

    // ---- Layer 2: GAT(256 -> 4x128, concat) + ReLU ----
    gemm_f32_kernel<<<dim3(512 / 64, gM), 256, 0, stream>>>(bufO, W2, bufH, N, 256, 512);
    al_kernel<<<gAL, 256, 0, stream>>>(bufH, as2, ad2, al_s, al_d, NH, 512, 128);
    stats_kernel<<<gNH, 256, 0, stream>>>(row_ptr, csrc, al_s, al_d, mmax, denom, NH);
    agg_kernel<<<N, 256, 0, stream>>>(row_ptr, csrc, bufH, al_s, al_d, mmax, denom,
                                      b2, bufO, 512, 128, 0, 1);

    // ---- Layer 3: GAT(512 -> 4x32, mean) -> z_mean ----
    gemm_f32_kernel<<<dim3(128 / 64, gM), 256, 0, stream>>>(bufO, Wm, bufH, N, 512, 128);
    al_kernel<<<gAL, 256, 0, stream>>>(bufH, a_sm, a_dm, al_s, al_d, NH, 128, 32);
    stats_kernel<<<gNH, 256, 0, stream>>>(row_ptr, csrc, al_s, al_d, mmax, denom, NH);
    agg_kernel<<<N, 256, 0, stream>>>(row_ptr, csrc, bufH, al_s, al_d, mmax, denom,
                                      bm, outp, 128, 32, 1, 0);

    // ---- Layer 4: GAT(512 -> 4x32, mean) -> z_logstd ----
    gemm_f32_kernel<<<dim3(128 / 64, gM), 256, 0, stream>>>(bufO, Wl, bufH, N, 512, 128);
    al_kernel<<<gAL, 256, 0, stream>>>(bufH, a_sl, a_dl, al_s, al_d, NH, 128, 32);
    stats_kernel<<<gNH, 256, 0, stream>>>(row_ptr, csrc, al_s, al_d, mmax, denom, NH);
    agg_kernel<<<N, 256, 0, stream>>>(row_ptr, csrc, bufH, al_s, al_d, mmax, denom,
                                      bl, outp + (size_t)N * 32, 128, 32, 1, 0);
}

// Round 2
// 1055.942 us; speedup vs baseline: 1.1510x; 1.1510x over previous
//
#include <hip/hip_runtime.h>
#include <cstddef>

#define HEADS 4

// ---------------- CSR build ----------------

__global__ void zero_int_kernel(int* __restrict__ p, int n) {
    int i = blockIdx.x * blockDim.x + threadIdx.x;
    if (i < n) p[i] = 0;
}

__global__ void count_edges_kernel(const int* __restrict__ ei, int E, int N,
                                   int* __restrict__ cnt) {
    int e = blockIdx.x * blockDim.x + threadIdx.x;
    if (e >= E + N) return;
    int d = (e < E) ? ei[E + e] : (e - E);  // self loops appended
    atomicAdd(&cnt[d], 1);
}

__global__ void scan_kernel(const int* __restrict__ cnt, int* __restrict__ rp, int n) {
    __shared__ int sh[1024];
    int t = threadIdx.x;
    int run = 0;
    if (t == 0) rp[0] = 0;
    for (int base = 0; base < n; base += 1024) {
        int v = (base + t < n) ? cnt[base + t] : 0;
        sh[t] = v;
        __syncthreads();
        for (int off = 1; off < 1024; off <<= 1) {
            int add = (t >= off) ? sh[t - off] : 0;
            __syncthreads();
            sh[t] += add;
            __syncthreads();
        }
        if (base + t < n) rp[base + t + 1] = run + sh[t];
        run += sh[1023];
        __syncthreads();
    }
}

__global__ void scatter_edges_kernel(const int* __restrict__ ei, int E, int N,
                                     const int* __restrict__ rp, int* __restrict__ cur,
                                     int* __restrict__ csrc, int* __restrict__ cdst) {
    int e = blockIdx.x * blockDim.x + threadIdx.x;
    if (e >= E + N) return;
    int s, d;
    if (e < E) { s = ei[e]; d = ei[E + e]; } else { s = e - E; d = s; }
    int pos = rp[d] + atomicAdd(&cur[d], 1);
    csrc[pos] = s;
    cdst[pos] = d;
}

// ---------------- f32 GEMM: C[M,Nc] = A[M,K] @ B[K,Nc] ----------------
// 128x128 tile, 256 threads, 8x8 per thread. K % 16 == 0, Nc % 128 == 0.

__global__ __launch_bounds__(256) void gemm128_kernel(
    const float* __restrict__ A, const float* __restrict__ B,
    float* __restrict__ C, int M, int K, int Nc) {
    __shared__ float As[16][132];  // [k][m], pad 132: staging writes are 2-way (free)
    __shared__ float Bs[16][132];  // [k][n]
    int tid = threadIdx.x;
    int bm = blockIdx.y * 128;
    int bn = blockIdx.x * 128;
    int tx = tid & 15;   // n-group (8 cols each)
    int ty = tid >> 4;   // m-group (8 rows each)
    float acc[8][8] = {};
    // A staging: 128 rows x 16 k = 512 float4; thread loads rows ar0, ar0+64
    int ar0 = tid >> 2;          // 0..63
    int ak  = (tid & 3) * 4;     // 0,4,8,12
    // B staging: 16 rows x 128 cols = 512 float4; thread loads k-rows bk0, bk0+8
    int bk0 = tid >> 5;          // 0..7
    int bn0 = (tid & 31) * 4;    // 0..124
    for (int k0 = 0; k0 < K; k0 += 16) {
        float4 va0 = make_float4(0.f, 0.f, 0.f, 0.f);
        float4 va1 = make_float4(0.f, 0.f, 0.f, 0.f);
        if (bm + ar0 < M)      va0 = *(const float4*)(A + (size_t)(bm + ar0) * K + k0 + ak);
        if (bm + ar0 + 64 < M) va1 = *(const float4*)(A + (size_t)(bm + ar0 + 64) * K + k0 + ak);
        float4 vb0 = *(const float4*)(B + (size_t)(k0 + bk0) * Nc + bn + bn0);
        float4 vb1 = *(const float4*)(B + (size_t)(k0 + bk0 + 8) * Nc + bn + bn0);
        As[ak + 0][ar0] = va0.x; As[ak + 1][ar0] = va0.y;
        As[ak + 2][ar0] = va0.z; As[ak + 3][ar0] = va0.w;
        As[ak + 0][ar0 + 64] = va1.x; As[ak + 1][ar0 + 64] = va1.y;
        As[ak + 2][ar0 + 64] = va1.z; As[ak + 3][ar0 + 64] = va1.w;
        *(float4*)&Bs[bk0][bn0]     = vb0;
        *(float4*)&Bs[bk0 + 8][bn0] = vb1;
        __syncthreads();
#pragma unroll
        for (int k = 0; k < 16; k++) {
            float a[8], b[8];
            *(float4*)(a)     = *(const float4*)&As[k][ty * 8];
            *(float4*)(a + 4) = *(const float4*)&As[k][ty * 8 + 4];
            *(float4*)(b)     = *(const float4*)&Bs[k][tx * 8];
            *(float4*)(b + 4) = *(const float4*)&Bs[k][tx * 8 + 4];
#pragma unroll
            for (int i = 0; i < 8; i++)
#pragma unroll
                for (int j = 0; j < 8; j++) acc[i][j] += a[i] * b[j];
        }
        __syncthreads();
    }
#pragma unroll
    for (int i = 0; i < 8; i++) {
        int m = bm + ty * 8 + i;
        if (m < M) {
            float* cp = C + (size_t)m * Nc + bn + tx * 8;
            *(float4*)(cp)     = make_float4(acc[i][0], acc[i][1], acc[i][2], acc[i][3]);
            *(float4*)(cp + 4) = make_float4(acc[i][4], acc[i][5], acc[i][6], acc[i][7]);
        }
    }
}

// ---------------- attention logits: al[n,h] = sum_c h[n,h,c]*a[h,c] ----------------
// one wave per (n, head)

__global__ __launch_bounds__(256) void al_kernel(
    const float* __restrict__ h, const float* __restrict__ a_src,
    const float* __restrict__ a_dst, float* __restrict__ al_s,
    float* __restrict__ al_d, int NH, int HC, int C) {
    int wid = blockIdx.x * 4 + (threadIdx.x >> 6);
    int lane = threadIdx.x & 63;
    if (wid >= NH) return;
    int n = wid >> 2;
    int hh = wid & 3;
    const float* row = h + (size_t)n * HC + hh * C;
    float s1 = 0.f, s2 = 0.f;
    for (int c = lane; c < C; c += 64) {
        float v = row[c];
        s1 += v * a_src[hh * C + c];
        s2 += v * a_dst[hh * C + c];
    }
#pragma unroll
    for (int off = 32; off > 0; off >>= 1) {
        s1 += __shfl_down(s1, off);
        s2 += __shfl_down(s2, off);
    }
    if (lane == 0) { al_s[wid] = s1; al_d[wid] = s2; }
}

// ---------------- segment softmax stats (max + expsum), thread per (dst,head) ----------------

__global__ void stats_kernel(const int* __restrict__ rp, const int* __restrict__ csrc,
                             const float* __restrict__ al_s, const float* __restrict__ al_d,
                             float* __restrict__ mmax, float* __restrict__ denom, int NH) {
    int t = blockIdx.x * blockDim.x + threadIdx.x;
    if (t >= NH) return;
    int n = t >> 2;
    int hh = t & 3;
    int beg = rp[n], end = rp[n + 1];
    float ad = al_d[t];
    float m = -3.402823466e38f;
    for (int e = beg; e < end; ++e) {
        float v = al_s[csrc[e] * HEADS + hh] + ad;
        v = v > 0.f ? v : 0.2f * v;
        m = fmaxf(m, v);
    }
    float sum = 0.f;
    for (int e = beg; e < end; ++e) {
        float v = al_s[csrc[e] * HEADS + hh] + ad;
        v = v > 0.f ? v : 0.2f * v;
        sum += __expf(v - m);
    }
    mmax[t] = m;
    denom[t] = sum;
}

// ---------------- per-edge alpha: alpha4[e][h] ----------------

__global__ __launch_bounds__(256) void alpha_kernel(
    const int* __restrict__ csrc, const int* __restrict__ cdst,
    const float* __restrict__ al_s, const float* __restrict__ al_d,
    const float* __restrict__ mmax, const float* __restrict__ denom,
    float* __restrict__ alpha4, int ET) {
    int e = blockIdx.x * blockDim.x + threadIdx.x;
    if (e >= ET) return;
    int s = csrc[e], d = cdst[e];
    float4 as = *(const float4*)(al_s + (size_t)s * 4);
    float4 ad = *(const float4*)(al_d + (size_t)d * 4);
    float4 m  = *(const float4*)(mmax + (size_t)d * 4);
    float4 dn = *(const float4*)(denom + (size_t)d * 4);
    float4 o;
    float v;
    v = as.x + ad.x; v = v > 0.f ? v : 0.2f * v; o.x = __expf(v - m.x) / (dn.x + 1e-16f);
    v = as.y + ad.y; v = v > 0.f ? v : 0.2f * v; o.y = __expf(v - m.y) / (dn.y + 1e-16f);
    v = as.z + ad.z; v = v > 0.f ? v : 0.2f * v; o.z = __expf(v - m.z) / (dn.z + 1e-16f);
    v = as.w + ad.w; v = v > 0.f ? v : 0.2f * v; o.w = __expf(v - m.w) / (dn.w + 1e-16f);
    *(float4*)(alpha4 + (size_t)e * 4) = o;
}

// ---------------- aggregate: block per dst node, CPT channels/thread ----------------

template <int CPT>
__global__ __launch_bounds__(256) void agg_kernel(
    const int* __restrict__ rp, const int* __restrict__ csrc,
    const float* __restrict__ alpha4, const float* __restrict__ h,
    const float* __restrict__ bias, float* __restrict__ out,
    int HC, int C, int do_mean, int do_relu) {
    __shared__ float sh[512];
    int n = blockIdx.x;
    int tid = threadIdx.x;
    int B = blockDim.x;
    int beg = rp[n], end = rp[n + 1];
    int ch[CPT], hh[CPT];
    float acc[CPT];
#pragma unroll
    for (int j = 0; j < CPT; j++) {
        ch[j] = tid + j * B;
        hh[j] = ch[j] / C;
        acc[j] = 0.f;
    }
    for (int e = beg; e < end; ++e) {
        int s = csrc[e];
        const float* row = h + (size_t)s * HC;
        const float* ap = alpha4 + (size_t)e * 4;
#pragma unroll
        for (int j = 0; j < CPT; j++) acc[j] += ap[hh[j]] * row[ch[j]];
    }
    if (!do_mean) {
#pragma unroll
        for (int j = 0; j < CPT; j++) {
            float v = acc[j] + bias[ch[j]];
            if (do_relu) v = fmaxf(v, 0.f);
            out[(size_t)n * HC + ch[j]] = v;
        }
    } else {
#pragma unroll
        for (int j = 0; j < CPT; j++) sh[ch[j]] = acc[j];
        __syncthreads();
        if (tid < C) {
            float v = (sh[tid] + sh[C + tid] + sh[2 * C + tid] + sh[3 * C + tid]) * 0.25f
                      + bias[tid];
            out[(size_t)n * C + tid] = v;
        }
    }
}

// ---------------- orchestration ----------------

extern "C" void kernel_launch(void* const* d_in, const int* in_sizes, int n_in,
                              void* d_out, int out_size, void* d_ws, size_t ws_size,
                              hipStream_t stream) {
    (void)n_in; (void)out_size; (void)ws_size;
    const float* x   = (const float*)d_in[0];
    const int*   ei  = (const int*)d_in[1];
    const float* W1  = (const float*)d_in[2];
    const float* as1 = (const float*)d_in[3];
    const float* ad1 = (const float*)d_in[4];
    const float* b1  = (const float*)d_in[5];
    const float* W2  = (const float*)d_in[6];
    const float* as2 = (const float*)d_in[7];
    const float* ad2 = (const float*)d_in[8];
    const float* b2  = (const float*)d_in[9];
    const float* Wm  = (const float*)d_in[10];
    const float* a_sm = (const float*)d_in[11];
    const float* a_dm = (const float*)d_in[12];
    const float* bm  = (const float*)d_in[13];
    const float* Wl  = (const float*)d_in[14];
    const float* a_sl = (const float*)d_in[15];
    const float* a_dl = (const float*)d_in[16];
    const float* bl  = (const float*)d_in[17];
    float* outp = (float*)d_out;

    const int N  = in_sizes[0] / 256;   // 30000
    const int E  = in_sizes[1] / 2;     // 480000
    const int ET = E + N;               // with self loops
    const int NH = N * HEADS;

    // workspace carve-up (all 256B-aligned)
    auto align_up = [](size_t v) { return (v + 255) & ~(size_t)255; };
    char* w = (char*)d_ws;
    int* row_ptr = (int*)w;  w += align_up((size_t)(N + 1) * 4);
    int* cnt     = (int*)w;  w += align_up((size_t)N * 4);
    int* csrc    = (int*)w;  w += align_up((size_t)ET * 4);
    int* cdst    = (int*)w;  w += align_up((size_t)ET * 4);
    float* al_s  = (float*)w; w += align_up((size_t)NH * 4);
    float* al_d  = (float*)w; w += align_up((size_t)NH * 4);
    float* mmax  = (float*)w; w += align_up((size_t)NH * 4);
    float* denom = (float*)w; w += align_up((size_t)NH * 4);
    float* alpha = (float*)w; w += align_up((size_t)ET * 4 * 4);
    float* bufH  = (float*)w; w += align_up((size_t)N * 512 * 4);
    float* bufO  = (float*)w; w += align_up((size_t)N * 512 * 4);

    // ---- CSR build (graph identical for all 4 layers) ----
    int gzN = (N + 255) / 256;
    int gzE = (ET + 255) / 256;
    zero_int_kernel<<<gzN, 256, 0, stream>>>(cnt, N);
    count_edges_kernel<<<gzE, 256, 0, stream>>>(ei, E, N, cnt);
    scan_kernel<<<1, 1024, 0, stream>>>(cnt, row_ptr, N);
    zero_int_kernel<<<gzN, 256, 0, stream>>>(cnt, N);
    scatter_edges_kernel<<<gzE, 256, 0, stream>>>(ei, E, N, row_ptr, cnt, csrc, cdst);

    int gNH = (NH + 255) / 256;
    int gAL = (NH + 3) / 4;
    int gE  = (ET + 255) / 256;
    int gM128 = (N + 127) / 128;

    // ---- Layer 1: GAT(256 -> 4x64, concat) + ReLU ----
    gemm128_kernel<<<dim3(256 / 128, gM128), 256, 0, stream>>>(x, W1, bufH, N, 256, 256);
    al_kernel<<<gAL, 256, 0, stream>>>(bufH, as1, ad1, al_s, al_d, NH, 256, 64);
    stats_kernel<<<gNH, 256, 0, stream>>>(row_ptr, csrc, al_s, al_d, mmax, denom, NH);
    alpha_kernel<<<gE, 256, 0, stream>>>(csrc, cdst, al_s, al_d, mmax, denom, alpha, ET);
    agg_kernel<1><<<N, 256, 0, stream>>>(row_ptr, csrc, alpha, bufH, b1, bufO, 256, 64, 0, 1);

    // ---- Layer 2: GAT(256 -> 4x128, concat) + ReLU ----
    gemm128_kernel<<<dim3(512 / 128, gM128), 256, 0, stream>>>(bufO, W2, bufH, N, 256, 512);
    al_kernel<<<gAL, 256, 0, stream>>>(bufH, as2, ad2, al_s, al_d, NH, 512, 128);
    stats_kernel<<<gNH, 256, 0, stream>>>(row_ptr, csrc, al_s, al_d, mmax, denom, NH);
    alpha_kernel<<<gE, 256, 0, stream>>>(csrc, cdst, al_s, al_d, mmax, denom, alpha, ET);
    agg_kernel<2><<<N, 256, 0, stream>>>(row_ptr, csrc, alpha, bufH, b2, bufO, 512, 128, 0, 1);

    // ---- Layer 3: GAT(512 -> 4x32, mean) -> z_mean ----
    gemm128_kernel<<<dim3(128 / 128, gM128), 256, 0, stream>>>(bufO, Wm, bufH, N, 512, 128);
    al_kernel<<<gAL, 256, 0, stream>>>(bufH, a_sm, a_dm, al_s, al_d, NH, 128, 32);
    stats_kernel<<<gNH, 256, 0, stream>>>(row_ptr, csrc, al_s, al_d, mmax, denom, NH);
    alpha_kernel<<<gE, 256, 0, stream>>>(csrc, cdst, al_s, al_d, mmax, denom, alpha, ET);
    agg_kernel<1><<<N, 128, 0, stream>>>(row_ptr, csrc, alpha, bufH, bm, outp, 128, 32, 1, 0);

    // ---- Layer 4: GAT(512 -> 4x32, mean) -> z_logstd ----
    gemm128_kernel<<<dim3(128 / 128, gM128), 256, 0, stream>>>(bufO, Wl, bufH, N, 512, 128);
    al_kernel<<<gAL, 256, 0, stream>>>(bufH, a_sl, a_dl, al_s, al_d, NH, 128, 32);
    stats_kernel<<<gNH, 256, 0, stream>>>(row_ptr, csrc, al_s, al_d, mmax, denom, NH);
    alpha_kernel<<<gE, 256, 0, stream>>>(csrc, cdst, al_s, al_d, mmax, denom, alpha, ET);
    agg_kernel<1><<<N, 128, 0, stream>>>(row_ptr, csrc, alpha, bufH, bl,
                                         outp + (size_t)N * 32, 128, 32, 1, 0);
}

// Round 3
// 637.644 us; speedup vs baseline: 1.9061x; 1.6560x over previous
//
#include <hip/hip_runtime.h>
#include <cstddef>

#define HEADS 4

typedef __attribute__((ext_vector_type(8))) short short8;
typedef __attribute__((ext_vector_type(4))) float f32x4;

__device__ __forceinline__ float b2f(unsigned short u) {
    union { unsigned int i; float f; } x; x.i = ((unsigned int)u) << 16; return x.f;
}
__device__ __forceinline__ unsigned short f2b(float f) {
    union { float f; unsigned int i; } x; x.f = f;
    unsigned int r = x.i + 0x7FFF + ((x.i >> 16) & 1);
    return (unsigned short)(r >> 16);
}

// ---------------- CSR build ----------------

__global__ void zero_int_kernel(int* __restrict__ p, int n) {
    int i = blockIdx.x * blockDim.x + threadIdx.x;
    if (i < n) p[i] = 0;
}

__global__ void count_edges_kernel(const int* __restrict__ ei, int E, int N,
                                   int* __restrict__ cnt) {
    int e = blockIdx.x * blockDim.x + threadIdx.x;
    if (e >= E + N) return;
    int d = (e < E) ? ei[E + e] : (e - E);  // self loops appended
    atomicAdd(&cnt[d], 1);
}

__global__ void scan_kernel(const int* __restrict__ cnt, int* __restrict__ rp, int n) {
    __shared__ int sh[1024];
    int t = threadIdx.x;
    int run = 0;
    if (t == 0) rp[0] = 0;
    for (int base = 0; base < n; base += 1024) {
        int v = (base + t < n) ? cnt[base + t] : 0;
        sh[t] = v;
        __syncthreads();
        for (int off = 1; off < 1024; off <<= 1) {
            int add = (t >= off) ? sh[t - off] : 0;
            __syncthreads();
            sh[t] += add;
            __syncthreads();
        }
        if (base + t < n) rp[base + t + 1] = run + sh[t];
        run += sh[1023];
        __syncthreads();
    }
}

__global__ void scatter_edges_kernel(const int* __restrict__ ei, int E, int N,
                                     const int* __restrict__ rp, int* __restrict__ cur,
                                     int* __restrict__ csrc, int* __restrict__ cdst) {
    int e = blockIdx.x * blockDim.x + threadIdx.x;
    if (e >= E + N) return;
    int s, d;
    if (e < E) { s = ei[e]; d = ei[E + e]; } else { s = e - E; d = s; }
    int pos = rp[d] + atomicAdd(&cur[d], 1);
    csrc[pos] = s;
    cdst[pos] = d;
}

// ---------------- dtype prep ----------------

// f32 [rows, cols] -> bf16 [padRows, cols], pad rows zeroed
__global__ void f32_to_bf16_pad_kernel(const float* __restrict__ in,
                                       unsigned short* __restrict__ out,
                                       int rows, int cols, int padRows) {
    int i = blockIdx.x * blockDim.x + threadIdx.x;
    if (i >= padRows * cols) return;
    int r = i / cols;
    out[i] = (r < rows) ? f2b(in[i]) : (unsigned short)0;
}

// W f32 [K, Nc] -> Wt bf16 [Nc, K]
__global__ void transpose_w_kernel(const float* __restrict__ W,
                                   unsigned short* __restrict__ Wt, int K, int Nc) {
    int i = blockIdx.x * blockDim.x + threadIdx.x;
    if (i >= K * Nc) return;
    int k = i / Nc, n = i - k * Nc;
    Wt[(size_t)n * K + k] = f2b(W[i]);
}

// ---------------- bf16 MFMA GEMM: C[M,Nc] = A[Mp,K] @ Bt[Nc,K]^T ----------------
// 128x128 tile, BK=32, 256 threads (4 waves in 2x2), mfma_f32_16x16x32_bf16.
// A must be padded to gridDim.y*128 rows (finite garbage ok); K%32==0, Nc%128==0.

__global__ __launch_bounds__(256) void gemm_bf16_kernel(
    const unsigned short* __restrict__ A, const unsigned short* __restrict__ Bt,
    unsigned short* __restrict__ C, int M, int K, int Nc) {
    __shared__ short As[128 * 32];
    __shared__ short Bs[128 * 32];
    int tid = threadIdx.x;
    int bm = blockIdx.y * 128;
    int bn = blockIdx.x * 128;
    int wave = tid >> 6, lane = tid & 63;
    int wm = (wave >> 1) * 64, wn = (wave & 1) * 64;
    int lm = lane & 15, lq = lane >> 4;

    f32x4 acc[4][4] = {};

    // staging: 512 chunks of 8 shorts; chunk c -> row c>>2, k-offset (c&3)*8
    int c0 = tid, c1 = tid + 256;
    const unsigned short* Ap0 = A + (size_t)(bm + (c0 >> 2)) * K + (c0 & 3) * 8;
    const unsigned short* Ap1 = A + (size_t)(bm + (c1 >> 2)) * K + (c1 & 3) * 8;
    const unsigned short* Bp0 = Bt + (size_t)(bn + (c0 >> 2)) * K + (c0 & 3) * 8;
    const unsigned short* Bp1 = Bt + (size_t)(bn + (c1 >> 2)) * K + (c1 & 3) * 8;

    for (int kk = 0; kk < K; kk += 32) {
        short8 a0 = *(const short8*)(Ap0 + kk);
        short8 a1 = *(const short8*)(Ap1 + kk);
        short8 b0 = *(const short8*)(Bp0 + kk);
        short8 b1 = *(const short8*)(Bp1 + kk);
        __syncthreads();  // previous iter's LDS reads done
        *(short8*)&As[c0 * 8] = a0;
        *(short8*)&As[c1 * 8] = a1;
        *(short8*)&Bs[c0 * 8] = b0;
        *(short8*)&Bs[c1 * 8] = b1;
        __syncthreads();
        short8 af[4], bf[4];
#pragma unroll
        for (int t = 0; t < 4; t++) {
            af[t] = *(const short8*)&As[(wm + t * 16 + lm) * 32 + lq * 8];
            bf[t] = *(const short8*)&Bs[(wn + t * 16 + lm) * 32 + lq * 8];
        }
#pragma unroll
        for (int tm = 0; tm < 4; tm++)
#pragma unroll
            for (int tn = 0; tn < 4; tn++)
                acc[tm][tn] = __builtin_amdgcn_mfma_f32_16x16x32_bf16(
                    af[tm], bf[tn], acc[tm][tn], 0, 0, 0);
    }
#pragma unroll
    for (int tm = 0; tm < 4; tm++) {
#pragma unroll
        for (int r = 0; r < 4; r++) {
            int row = bm + wm + tm * 16 + lq * 4 + r;
            if (row < M) {
#pragma unroll
                for (int tn = 0; tn < 4; tn++) {
                    int col = bn + wn + tn * 16 + lm;
                    C[(size_t)row * Nc + col] = f2b(acc[tm][tn][r]);
                }
            }
        }
    }
}

// ---------------- attention logits from bf16 h ----------------
// one wave per (n, head)

__global__ __launch_bounds__(256) void al_kernel(
    const unsigned short* __restrict__ h, const float* __restrict__ a_src,
    const float* __restrict__ a_dst, float* __restrict__ al_s,
    float* __restrict__ al_d, int NH, int HC, int C) {
    int wid = blockIdx.x * 4 + (threadIdx.x >> 6);
    int lane = threadIdx.x & 63;
    if (wid >= NH) return;
    int n = wid >> 2;
    int hh = wid & 3;
    const unsigned short* row = h + (size_t)n * HC + hh * C;
    float s1 = 0.f, s2 = 0.f;
    for (int c = lane; c < C; c += 64) {
        float v = b2f(row[c]);
        s1 += v * a_src[hh * C + c];
        s2 += v * a_dst[hh * C + c];
    }
#pragma unroll
    for (int off = 32; off > 0; off >>= 1) {
        s1 += __shfl_down(s1, off);
        s2 += __shfl_down(s2, off);
    }
    if (lane == 0) { al_s[wid] = s1; al_d[wid] = s2; }
}

// ---------------- segment softmax stats: thread per dst node, float4 over heads ----------------

__global__ void stats_kernel(const int* __restrict__ rp, const int* __restrict__ csrc,
                             const float* __restrict__ al_s, const float* __restrict__ al_d,
                             float* __restrict__ mmax, float* __restrict__ denom, int N) {
    int n = blockIdx.x * blockDim.x + threadIdx.x;
    if (n >= N) return;
    int beg = rp[n], end = rp[n + 1];
    float4 ad = *(const float4*)(al_d + (size_t)n * 4);
    float mx = -3.402823466e38f, my = mx, mz = mx, mw = mx;
    for (int e = beg; e < end; ++e) {
        float4 as = *(const float4*)(al_s + (size_t)csrc[e] * 4);
        float v;
        v = as.x + ad.x; v = v > 0.f ? v : 0.2f * v; mx = fmaxf(mx, v);
        v = as.y + ad.y; v = v > 0.f ? v : 0.2f * v; my = fmaxf(my, v);
        v = as.z + ad.z; v = v > 0.f ? v : 0.2f * v; mz = fmaxf(mz, v);
        v = as.w + ad.w; v = v > 0.f ? v : 0.2f * v; mw = fmaxf(mw, v);
    }
    float sx = 0.f, sy = 0.f, sz = 0.f, sw = 0.f;
    for (int e = beg; e < end; ++e) {
        float4 as = *(const float4*)(al_s + (size_t)csrc[e] * 4);
        float v;
        v = as.x + ad.x; v = v > 0.f ? v : 0.2f * v; sx += __expf(v - mx);
        v = as.y + ad.y; v = v > 0.f ? v : 0.2f * v; sy += __expf(v - my);
        v = as.z + ad.z; v = v > 0.f ? v : 0.2f * v; sz += __expf(v - mz);
        v = as.w + ad.w; v = v > 0.f ? v : 0.2f * v; sw += __expf(v - mw);
    }
    *(float4*)(mmax + (size_t)n * 4) = make_float4(mx, my, mz, mw);
    *(float4*)(denom + (size_t)n * 4) = make_float4(sx, sy, sz, sw);
}

// ---------------- per-edge alpha ----------------

__global__ __launch_bounds__(256) void alpha_kernel(
    const int* __restrict__ csrc, const int* __restrict__ cdst,
    const float* __restrict__ al_s, const float* __restrict__ al_d,
    const float* __restrict__ mmax, const float* __restrict__ denom,
    float* __restrict__ alpha4, int ET) {
    int e = blockIdx.x * blockDim.x + threadIdx.x;
    if (e >= ET) return;
    int s = csrc[e], d = cdst[e];
    float4 as = *(const float4*)(al_s + (size_t)s * 4);
    float4 ad = *(const float4*)(al_d + (size_t)d * 4);
    float4 m  = *(const float4*)(mmax + (size_t)d * 4);
    float4 dn = *(const float4*)(denom + (size_t)d * 4);
    float4 o;
    float v;
    v = as.x + ad.x; v = v > 0.f ? v : 0.2f * v; o.x = __expf(v - m.x) / (dn.x + 1e-16f);
    v = as.y + ad.y; v = v > 0.f ? v : 0.2f * v; o.y = __expf(v - m.y) / (dn.y + 1e-16f);
    v = as.z + ad.z; v = v > 0.f ? v : 0.2f * v; o.z = __expf(v - m.z) / (dn.z + 1e-16f);
    v = as.w + ad.w; v = v > 0.f ? v : 0.2f * v; o.w = __expf(v - m.w) / (dn.w + 1e-16f);
    *(float4*)(alpha4 + (size_t)e * 4) = o;
}

// ---------------- aggregate: block per dst node, V channels/thread, bf16 h ----------------
// blockDim.x == HC/V. Requires C % V == 0 so all V channels share a head.
// concat path writes bf16 (ushort) rows; mean path writes f32 to out.

template <int V>
__global__ void agg_kernel(const int* __restrict__ rp, const int* __restrict__ csrc,
                           const float* __restrict__ alpha4,
                           const unsigned short* __restrict__ h,
                           const float* __restrict__ bias, void* __restrict__ outv,
                           int HC, int C, int do_mean, int do_relu) {
    __shared__ float sh[128];
    int n = blockIdx.x;
    int tid = threadIdx.x;
    int ch = tid * V;
    int hh = ch / C;
    int beg = rp[n], end = rp[n + 1];
    float acc[V];
#pragma unroll
    for (int j = 0; j < V; j++) acc[j] = 0.f;
    int e = beg;
    for (; e + 2 <= end; e += 2) {
        int s0 = csrc[e], s1 = csrc[e + 1];
        float a0 = alpha4[(size_t)e * 4 + hh];
        float a1 = alpha4[(size_t)(e + 1) * 4 + hh];
        const unsigned short* p0 = h + (size_t)s0 * HC + ch;
        const unsigned short* p1 = h + (size_t)s1 * HC + ch;
        if constexpr (V == 4) {
            ushort4 u0 = *(const ushort4*)p0;
            ushort4 u1 = *(const ushort4*)p1;
            acc[0] += a0 * b2f(u0.x) + a1 * b2f(u1.x);
            acc[1] += a0 * b2f(u0.y) + a1 * b2f(u1.y);
            acc[2] += a0 * b2f(u0.z) + a1 * b2f(u1.z);
            acc[3] += a0 * b2f(u0.w) + a1 * b2f(u1.w);
        } else {
            ushort2 u0 = *(const ushort2*)p0;
            ushort2 u1 = *(const ushort2*)p1;
            acc[0] += a0 * b2f(u0.x) + a1 * b2f(u1.x);
            acc[1] += a0 * b2f(u0.y) + a1 * b2f(u1.y);
        }
    }
    if (e < end) {
        int s0 = csrc[e];
        float a0 = alpha4[(size_t)e * 4 + hh];
        const unsigned short* p0 = h + (size_t)s0 * HC + ch;
        if constexpr (V == 4) {
            ushort4 u0 = *(const ushort4*)p0;
            acc[0] += a0 * b2f(u0.x);
            acc[1] += a0 * b2f(u0.y);
            acc[2] += a0 * b2f(u0.z);
            acc[3] += a0 * b2f(u0.w);
        } else {
            ushort2 u0 = *(const ushort2*)p0;
            acc[0] += a0 * b2f(u0.x);
            acc[1] += a0 * b2f(u0.y);
        }
    }
    if (!do_mean) {
        unsigned short* out = (unsigned short*)outv;
        unsigned short o[V];
#pragma unroll
        for (int j = 0; j < V; j++) {
            float v = acc[j] + bias[ch + j];
            if (do_relu) v = fmaxf(v, 0.f);
            o[j] = f2b(v);
        }
        if constexpr (V == 4) {
            *(ushort4*)(out + (size_t)n * HC + ch) = make_ushort4(o[0], o[1], o[2], o[3]);
        } else {
            *(ushort2*)(out + (size_t)n * HC + ch) = make_ushort2(o[0], o[1]);
        }
    } else {
        float* out = (float*)outv;
#pragma unroll
        for (int j = 0; j < V; j++) sh[ch + j] = acc[j];
        __syncthreads();
        if (tid < C) {
            float v = (sh[tid] + sh[C + tid] + sh[2 * C + tid] + sh[3 * C + tid]) * 0.25f
                      + bias[tid];
            out[(size_t)n * C + tid] = v;
        }
    }
}

// ---------------- orchestration ----------------

extern "C" void kernel_launch(void* const* d_in, const int* in_sizes, int n_in,
                              void* d_out, int out_size, void* d_ws, size_t ws_size,
                              hipStream_t stream) {
    (void)n_in; (void)out_size; (void)ws_size;
    const float* x   = (const float*)d_in[0];
    const int*   ei  = (const int*)d_in[1];
    const float* W1  = (const float*)d_in[2];
    const float* as1 = (const float*)d_in[3];
    const float* ad1 = (const float*)d_in[4];
    const float* b1  = (const float*)d_in[5];
    const float* W2  = (const float*)d_in[6];
    const float* as2 = (const float*)d_in[7];
    const float* ad2 = (const float*)d_in[8];
    const float* b2  = (const float*)d_in[9];
    const float* Wm  = (const float*)d_in[10];
    const float* a_sm = (const float*)d_in[11];
    const float* a_dm = (const float*)d_in[12];
    const float* bm  = (const float*)d_in[13];
    const float* Wl  = (const float*)d_in[14];
    const float* a_sl = (const float*)d_in[15];
    const float* a_dl = (const float*)d_in[16];
    const float* bl  = (const float*)d_in[17];
    float* outp = (float*)d_out;

    const int N  = in_sizes[0] / 256;   // 30000
    const int E  = in_sizes[1] / 2;     // 480000
    const int ET = E + N;               // with self loops
    const int NH = N * HEADS;
    const int gM = (N + 127) / 128;     // 235
    const int Mp = gM * 128;            // 30080 (padded rows)

    auto align_up = [](size_t v) { return (v + 255) & ~(size_t)255; };
    char* w = (char*)d_ws;
    int* row_ptr = (int*)w;  w += align_up((size_t)(N + 1) * 4);
    int* cnt     = (int*)w;  w += align_up((size_t)N * 4);
    int* csrc    = (int*)w;  w += align_up((size_t)ET * 4);
    int* cdst    = (int*)w;  w += align_up((size_t)ET * 4);
    float* al_s  = (float*)w; w += align_up((size_t)NH * 4);
    float* al_d  = (float*)w; w += align_up((size_t)NH * 4);
    float* mmax  = (float*)w; w += align_up((size_t)NH * 4);
    float* denom = (float*)w; w += align_up((size_t)NH * 4);
    float* alpha = (float*)w; w += align_up((size_t)ET * 4 * 4);
    unsigned short* xb   = (unsigned short*)w; w += align_up((size_t)Mp * 256 * 2);
    unsigned short* W1t  = (unsigned short*)w; w += align_up((size_t)256 * 256 * 2);
    unsigned short* W2t  = (unsigned short*)w; w += align_up((size_t)512 * 256 * 2);
    unsigned short* Wmt  = (unsigned short*)w; w += align_up((size_t)128 * 512 * 2);
    unsigned short* Wlt  = (unsigned short*)w; w += align_up((size_t)128 * 512 * 2);
    unsigned short* bufH = (unsigned short*)w; w += align_up((size_t)N * 512 * 2);
    unsigned short* bufO = (unsigned short*)w; w += align_up((size_t)Mp * 512 * 2);

    // ---- CSR build ----
    int gzN = (N + 255) / 256;
    int gzE = (ET + 255) / 256;
    zero_int_kernel<<<gzN, 256, 0, stream>>>(cnt, N);
    count_edges_kernel<<<gzE, 256, 0, stream>>>(ei, E, N, cnt);
    scan_kernel<<<1, 1024, 0, stream>>>(cnt, row_ptr, N);
    zero_int_kernel<<<gzN, 256, 0, stream>>>(cnt, N);
    scatter_edges_kernel<<<gzE, 256, 0, stream>>>(ei, E, N, row_ptr, cnt, csrc, cdst);

    // ---- dtype prep ----
    f32_to_bf16_pad_kernel<<<((Mp * 256) + 255) / 256, 256, 0, stream>>>(x, xb, N, 256, Mp);
    transpose_w_kernel<<<(256 * 256 + 255) / 256, 256, 0, stream>>>(W1, W1t, 256, 256);
    transpose_w_kernel<<<(256 * 512 + 255) / 256, 256, 0, stream>>>(W2, W2t, 256, 512);
    transpose_w_kernel<<<(512 * 128 + 255) / 256, 256, 0, stream>>>(Wm, Wmt, 512, 128);
    transpose_w_kernel<<<(512 * 128 + 255) / 256, 256, 0, stream>>>(Wl, Wlt, 512, 128);

    int gAL = (NH + 3) / 4;
    int gStat = (N + 255) / 256;
    int gE = (ET + 255) / 256;

    // ---- Layer 1: GAT(256 -> 4x64, concat) + ReLU ----
    gemm_bf16_kernel<<<dim3(2, gM), 256, 0, stream>>>(xb, W1t, bufH, N, 256, 256);
    al_kernel<<<gAL, 256, 0, stream>>>(bufH, as1, ad1, al_s, al_d, NH, 256, 64);
    stats_kernel<<<gStat, 256, 0, stream>>>(row_ptr, csrc, al_s, al_d, mmax, denom, N);
    alpha_kernel<<<gE, 256, 0, stream>>>(csrc, cdst, al_s, al_d, mmax, denom, alpha, ET);
    agg_kernel<4><<<N, 64, 0, stream>>>(row_ptr, csrc, alpha, bufH, b1, bufO, 256, 64, 0, 1);

    // ---- Layer 2: GAT(256 -> 4x128, concat) + ReLU ----
    gemm_bf16_kernel<<<dim3(4, gM), 256, 0, stream>>>(bufO, W2t, bufH, N, 256, 512);
    al_kernel<<<gAL, 256, 0, stream>>>(bufH, as2, ad2, al_s, al_d, NH, 512, 128);
    stats_kernel<<<gStat, 256, 0, stream>>>(row_ptr, csrc, al_s, al_d, mmax, denom, N);
    alpha_kernel<<<gE, 256, 0, stream>>>(csrc, cdst, al_s, al_d, mmax, denom, alpha, ET);
    agg_kernel<4><<<N, 128, 0, stream>>>(row_ptr, csrc, alpha, bufH, b2, bufO, 512, 128, 0, 1);

    // ---- Layer 3: GAT(512 -> 4x32, mean) -> z_mean ----
    gemm_bf16_kernel<<<dim3(1, gM), 256, 0, stream>>>(bufO, Wmt, bufH, N, 512, 128);
    al_kernel<<<gAL, 256, 0, stream>>>(bufH, a_sm, a_dm, al_s, al_d, NH, 128, 32);
    stats_kernel<<<gStat, 256, 0, stream>>>(row_ptr, csrc, al_s, al_d, mmax, denom, N);
    alpha_kernel<<<gE, 256, 0, stream>>>(csrc, cdst, al_s, al_d, mmax, denom, alpha, ET);
    agg_kernel<2><<<N, 64, 0, stream>>>(row_ptr, csrc, alpha, bufH, bm, outp, 128, 32, 1, 0);

    // ---- Layer 4: GAT(512 -> 4x32, mean) -> z_logstd ----
    gemm_bf16_kernel<<<dim3(1, gM), 256, 0, stream>>>(bufO, Wlt, bufH, N, 512, 128);
    al_kernel<<<gAL, 256, 0, stream>>>(bufH, a_sl, a_dl, al_s, al_d, NH, 128, 32);
    stats_kernel<<<gStat, 256, 0, stream>>>(row_ptr, csrc, al_s, al_d, mmax, denom, N);
    alpha_kernel<<<gE, 256, 0, stream>>>(csrc, cdst, al_s, al_d, mmax, denom, alpha, ET);
    agg_kernel<2><<<N, 64, 0, stream>>>(row_ptr, csrc, alpha, bufH, bl,
                                        outp + (size_t)N * 32, 128, 32, 1, 0);
}

// Round 4
// 618.778 us; speedup vs baseline: 1.9642x; 1.0305x over previous
//
#include <hip/hip_runtime.h>
#include <cstddef>

typedef __attribute__((ext_vector_type(8))) short short8;
typedef __attribute__((ext_vector_type(4))) float f32x4;

__device__ __forceinline__ float b2f(unsigned short u) {
    union { unsigned int i; float f; } x; x.i = ((unsigned int)u) << 16; return x.f;
}
__device__ __forceinline__ unsigned short f2b(float f) {
    union { float f; unsigned int i; } x; x.f = f;
    unsigned int r = x.i + 0x7FFF + ((x.i >> 16) & 1);
    return (unsigned short)(r >> 16);
}
__device__ __forceinline__ float lrelu(float v) { return v > 0.f ? v : 0.2f * v; }

// ---------------- CSR build ----------------

__global__ void zero_int_kernel(int* __restrict__ p, int n) {
    int i = blockIdx.x * blockDim.x + threadIdx.x;
    if (i < n) p[i] = 0;
}

__global__ void count_edges_kernel(const int* __restrict__ ei, int E, int N,
                                   int* __restrict__ cnt) {
    int e = blockIdx.x * blockDim.x + threadIdx.x;
    if (e >= E + N) return;
    int d = (e < E) ? ei[E + e] : (e - E);  // self loops appended
    atomicAdd(&cnt[d], 1);
}

// single block, 1024 threads; per-thread serial chunk + one block scan
__global__ void scan_kernel(const int* __restrict__ cnt, int* __restrict__ rp, int n) {
    __shared__ int sh[1024];
    int t = threadIdx.x;
    int chunk = (n + 1023) >> 10;
    int beg = t * chunk;
    int end = beg + chunk < n ? beg + chunk : n;
    int local = 0;
    for (int i = beg; i < end; i++) local += cnt[i];
    sh[t] = local;
    __syncthreads();
    for (int off = 1; off < 1024; off <<= 1) {
        int v = (t >= off) ? sh[t - off] : 0;
        __syncthreads();
        sh[t] += v;
        __syncthreads();
    }
    int run = (t == 0) ? 0 : sh[t - 1];
    for (int i = beg; i < end; i++) { run += cnt[i]; rp[i + 1] = run; }
    if (t == 0) rp[0] = 0;
}

__global__ void scatter_edges_kernel(const int* __restrict__ ei, int E, int N,
                                     const int* __restrict__ rp, int* __restrict__ cur,
                                     int* __restrict__ csrc) {
    int e = blockIdx.x * blockDim.x + threadIdx.x;
    if (e >= E + N) return;
    int s, d;
    if (e < E) { s = ei[e]; d = ei[E + e]; } else { s = e - E; d = s; }
    int pos = rp[d] + atomicAdd(&cur[d], 1);
    csrc[pos] = s;
}

// ---------------- dtype prep ----------------

// f32 -> bf16, 4 elements/thread, pad rows zeroed. cols % 4 == 0.
__global__ void f32_to_bf16_pad4_kernel(const float* __restrict__ in,
                                        unsigned short* __restrict__ out,
                                        int rows, int cols, int padRows) {
    int i = blockIdx.x * blockDim.x + threadIdx.x;
    int total = (padRows * cols) >> 2;
    if (i >= total) return;
    int r = (i * 4) / cols;
    ushort4 o;
    if (r < rows) {
        float4 v = *(const float4*)(in + (size_t)i * 4);
        o = make_ushort4(f2b(v.x), f2b(v.y), f2b(v.z), f2b(v.w));
    } else {
        o = make_ushort4(0, 0, 0, 0);
    }
    *(ushort4*)(out + (size_t)i * 4) = o;
}

// W f32 [K, Nc] -> Wt bf16 [Nc, K]
__global__ void transpose_w_kernel(const float* __restrict__ W,
                                   unsigned short* __restrict__ Wt, int K, int Nc) {
    int i = blockIdx.x * blockDim.x + threadIdx.x;
    if (i >= K * Nc) return;
    int k = i / Nc, n = i - k * Nc;
    Wt[(size_t)n * K + k] = f2b(W[i]);
}

// ---------------- bf16 MFMA GEMM: C[M,Nc] = A[Mp,K] @ Bt[Nc,K]^T ----------------
// 128x128 tile, BK=32, 256 threads (4 waves in 2x2), mfma_f32_16x16x32_bf16.

__global__ __launch_bounds__(256) void gemm_bf16_kernel(
    const unsigned short* __restrict__ A, const unsigned short* __restrict__ Bt,
    unsigned short* __restrict__ C, int M, int K, int Nc) {
    __shared__ short As[128 * 32];
    __shared__ short Bs[128 * 32];
    int tid = threadIdx.x;
    int bm = blockIdx.y * 128;
    int bn = blockIdx.x * 128;
    int wave = tid >> 6, lane = tid & 63;
    int wm = (wave >> 1) * 64, wn = (wave & 1) * 64;
    int lm = lane & 15, lq = lane >> 4;

    f32x4 acc[4][4] = {};

    int c0 = tid, c1 = tid + 256;
    const unsigned short* Ap0 = A + (size_t)(bm + (c0 >> 2)) * K + (c0 & 3) * 8;
    const unsigned short* Ap1 = A + (size_t)(bm + (c1 >> 2)) * K + (c1 & 3) * 8;
    const unsigned short* Bp0 = Bt + (size_t)(bn + (c0 >> 2)) * K + (c0 & 3) * 8;
    const unsigned short* Bp1 = Bt + (size_t)(bn + (c1 >> 2)) * K + (c1 & 3) * 8;

    for (int kk = 0; kk < K; kk += 32) {
        short8 a0 = *(const short8*)(Ap0 + kk);
        short8 a1 = *(const short8*)(Ap1 + kk);
        short8 b0 = *(const short8*)(Bp0 + kk);
        short8 b1 = *(const short8*)(Bp1 + kk);
        __syncthreads();
        *(short8*)&As[c0 * 8] = a0;
        *(short8*)&As[c1 * 8] = a1;
        *(short8*)&Bs[c0 * 8] = b0;
        *(short8*)&Bs[c1 * 8] = b1;
        __syncthreads();
        short8 af[4], bf[4];
#pragma unroll
        for (int t = 0; t < 4; t++) {
            af[t] = *(const short8*)&As[(wm + t * 16 + lm) * 32 + lq * 8];
            bf[t] = *(const short8*)&Bs[(wn + t * 16 + lm) * 32 + lq * 8];
        }
#pragma unroll
        for (int tm = 0; tm < 4; tm++)
#pragma unroll
            for (int tn = 0; tn < 4; tn++)
                acc[tm][tn] = __builtin_amdgcn_mfma_f32_16x16x32_bf16(
                    af[tm], bf[tn], acc[tm][tn], 0, 0, 0);
    }
#pragma unroll
    for (int tm = 0; tm < 4; tm++) {
#pragma unroll
        for (int r = 0; r < 4; r++) {
            int row = bm + wm + tm * 16 + lq * 4 + r;
            if (row < M) {
#pragma unroll
                for (int tn = 0; tn < 4; tn++) {
                    int col = bn + wn + tn * 16 + lm;
                    C[(size_t)row * Nc + col] = f2b(acc[tm][tn][r]);
                }
            }
        }
    }
}

// ---------------- attention logits (H heads, hi pointers for heads 4..7) ----------------

__global__ __launch_bounds__(256) void al_kernel(
    const unsigned short* __restrict__ h,
    const float* __restrict__ aslo, const float* __restrict__ adlo,
    const float* __restrict__ ashi, const float* __restrict__ adhi,
    float* __restrict__ al_s, float* __restrict__ al_d,
    int NHtot, int HC, int C, int H) {
    int lane = threadIdx.x & 63;
    int wv = blockIdx.x * 4 + (threadIdx.x >> 6);
    if (C >= 64) {
        if (wv >= NHtot) return;
        int n = wv / H, hh = wv % H;
        const float* as_ = (hh < 4) ? (aslo + hh * C) : (ashi + (hh - 4) * C);
        const float* ad_ = (hh < 4) ? (adlo + hh * C) : (adhi + (hh - 4) * C);
        const unsigned short* row = h + (size_t)n * HC + hh * C;
        float s1 = 0.f, s2 = 0.f;
        for (int c = lane; c < C; c += 64) {
            float v = b2f(row[c]);
            s1 += v * as_[c];
            s2 += v * ad_[c];
        }
#pragma unroll
        for (int off = 32; off > 0; off >>= 1) {
            s1 += __shfl_down(s1, off);
            s2 += __shfl_down(s2, off);
        }
        if (lane == 0) { al_s[wv] = s1; al_d[wv] = s2; }
    } else {  // C == 32: two (n,head) pairs per wave
        int wid = wv * 2 + (lane >> 5);
        int widc = wid < NHtot ? wid : NHtot - 1;
        int n = widc / H, hh = widc % H;
        const float* as_ = (hh < 4) ? (aslo + hh * C) : (ashi + (hh - 4) * C);
        const float* ad_ = (hh < 4) ? (adlo + hh * C) : (adhi + (hh - 4) * C);
        int c = lane & 31;
        float v = b2f(h[(size_t)n * HC + hh * C + c]);
        float s1 = v * as_[c], s2 = v * ad_[c];
#pragma unroll
        for (int off = 16; off > 0; off >>= 1) {
            s1 += __shfl_down(s1, off);
            s2 += __shfl_down(s2, off);
        }
        if ((lane & 31) == 0 && wid < NHtot) { al_s[wid] = s1; al_d[wid] = s2; }
    }
}

// ---------------- fused segment-softmax stats + alpha write, thread per dst node ----------------
// H4 = number of float4 head-groups (1 -> 4 heads, 2 -> 8 heads). alpha stride = 4*H4.

template <int H4>
__global__ __launch_bounds__(256) void stats_alpha_kernel(
    const int* __restrict__ rp, const int* __restrict__ csrc,
    const float* __restrict__ al_s, const float* __restrict__ al_d,
    float* __restrict__ alpha, int N) {
    int n = blockIdx.x * blockDim.x + threadIdx.x;
    if (n >= N) return;
    const int H = 4 * H4;
    int beg = rp[n], end = rp[n + 1];
    float4 ad[H4], m[H4], sum[H4];
#pragma unroll
    for (int g = 0; g < H4; g++) {
        ad[g] = *(const float4*)(al_d + (size_t)n * H + g * 4);
        m[g] = make_float4(-3.402823466e38f, -3.402823466e38f,
                           -3.402823466e38f, -3.402823466e38f);
        sum[g] = make_float4(0.f, 0.f, 0.f, 0.f);
    }
    for (int e = beg; e < end; e++) {
        int s = csrc[e];
#pragma unroll
        for (int g = 0; g < H4; g++) {
            float4 as = *(const float4*)(al_s + (size_t)s * H + g * 4);
            m[g].x = fmaxf(m[g].x, lrelu(as.x + ad[g].x));
            m[g].y = fmaxf(m[g].y, lrelu(as.y + ad[g].y));
            m[g].z = fmaxf(m[g].z, lrelu(as.z + ad[g].z));
            m[g].w = fmaxf(m[g].w, lrelu(as.w + ad[g].w));
        }
    }
    for (int e = beg; e < end; e++) {
        int s = csrc[e];
#pragma unroll
        for (int g = 0; g < H4; g++) {
            float4 as = *(const float4*)(al_s + (size_t)s * H + g * 4);
            float4 ex;
            ex.x = __expf(lrelu(as.x + ad[g].x) - m[g].x);
            ex.y = __expf(lrelu(as.y + ad[g].y) - m[g].y);
            ex.z = __expf(lrelu(as.z + ad[g].z) - m[g].z);
            ex.w = __expf(lrelu(as.w + ad[g].w) - m[g].w);
            sum[g].x += ex.x; sum[g].y += ex.y; sum[g].z += ex.z; sum[g].w += ex.w;
            *(float4*)(alpha + (size_t)e * H + g * 4) = ex;
        }
    }
    float4 r[H4];
#pragma unroll
    for (int g = 0; g < H4; g++) {
        r[g].x = 1.0f / (sum[g].x + 1e-16f);
        r[g].y = 1.0f / (sum[g].y + 1e-16f);
        r[g].z = 1.0f / (sum[g].z + 1e-16f);
        r[g].w = 1.0f / (sum[g].w + 1e-16f);
    }
    for (int e = beg; e < end; e++) {
#pragma unroll
        for (int g = 0; g < H4; g++) {
            float4 a = *(const float4*)(alpha + (size_t)e * H + g * 4);
            a.x *= r[g].x; a.y *= r[g].y; a.z *= r[g].z; a.w *= r[g].w;
            *(float4*)(alpha + (size_t)e * H + g * 4) = a;
        }
    }
}

// ---------------- aggregate (concat layers): block(64) per dst node ----------------
// V channels/thread (one wave covers the full row), bias+ReLU, bf16 out.

template <int V, int H>
__global__ void agg_concat_kernel(
    const int* __restrict__ rp, const int* __restrict__ csrc,
    const float* __restrict__ alpha, const unsigned short* __restrict__ h,
    const float* __restrict__ bias, unsigned short* __restrict__ out,
    int HC, int C) {
    int n = blockIdx.x, tid = threadIdx.x;
    int ch = tid * V;
    int hh = ch / C;
    int beg = rp[n], end = rp[n + 1];
    float acc[V];
#pragma unroll
    for (int j = 0; j < V; j++) acc[j] = 0.f;
    int e = beg;
    for (; e + 4 <= end; e += 4) {
#pragma unroll
        for (int u = 0; u < 4; u++) {
            int s = csrc[e + u];
            float a = alpha[(size_t)(e + u) * H + hh];
            const unsigned short* p = h + (size_t)s * HC + ch;
            if constexpr (V == 8) {
                short8 uv = *(const short8*)p;
#pragma unroll
                for (int j = 0; j < 8; j++) acc[j] += a * b2f((unsigned short)uv[j]);
            } else {
                ushort4 u4 = *(const ushort4*)p;
                acc[0] += a * b2f(u4.x); acc[1] += a * b2f(u4.y);
                acc[2] += a * b2f(u4.z); acc[3] += a * b2f(u4.w);
            }
        }
    }
    for (; e < end; e++) {
        int s = csrc[e];
        float a = alpha[(size_t)e * H + hh];
        const unsigned short* p = h + (size_t)s * HC + ch;
        if constexpr (V == 8) {
            short8 uv = *(const short8*)p;
#pragma unroll
            for (int j = 0; j < 8; j++) acc[j] += a * b2f((unsigned short)uv[j]);
        } else {
            ushort4 u4 = *(const ushort4*)p;
            acc[0] += a * b2f(u4.x); acc[1] += a * b2f(u4.y);
            acc[2] += a * b2f(u4.z); acc[3] += a * b2f(u4.w);
        }
    }
    if constexpr (V == 8) {
        short8 o;
#pragma unroll
        for (int j = 0; j < 8; j++)
            o[j] = (short)f2b(fmaxf(acc[j] + bias[ch + j], 0.f));
        *(short8*)(out + (size_t)n * HC + ch) = o;
    } else {
        ushort4 o;
        o.x = f2b(fmaxf(acc[0] + bias[ch + 0], 0.f));
        o.y = f2b(fmaxf(acc[1] + bias[ch + 1], 0.f));
        o.z = f2b(fmaxf(acc[2] + bias[ch + 2], 0.f));
        o.w = f2b(fmaxf(acc[3] + bias[ch + 3], 0.f));
        *(ushort4*)(out + (size_t)n * HC + ch) = o;
    }
}

// ---------------- aggregate (batched L3+L4, 8 heads x 32ch, mean over head groups) ----------------
// 64 threads, V=4, HC=256. Heads 0-3 -> out1 (+b1), heads 4-7 -> out2 (+b2). f32 out.

__global__ void agg_mean2_kernel(
    const int* __restrict__ rp, const int* __restrict__ csrc,
    const float* __restrict__ alpha, const unsigned short* __restrict__ h,
    const float* __restrict__ b1, const float* __restrict__ b2,
    float* __restrict__ out1, float* __restrict__ out2) {
    __shared__ float sh[256];
    int n = blockIdx.x, tid = threadIdx.x;
    int ch = tid * 4;
    int hh = ch >> 5;
    int beg = rp[n], end = rp[n + 1];
    float acc[4] = {0.f, 0.f, 0.f, 0.f};
    int e = beg;
    for (; e + 4 <= end; e += 4) {
#pragma unroll
        for (int u = 0; u < 4; u++) {
            int s = csrc[e + u];
            float a = alpha[(size_t)(e + u) * 8 + hh];
            ushort4 u4 = *(const ushort4*)(h + (size_t)s * 256 + ch);
            acc[0] += a * b2f(u4.x); acc[1] += a * b2f(u4.y);
            acc[2] += a * b2f(u4.z); acc[3] += a * b2f(u4.w);
        }
    }
    for (; e < end; e++) {
        int s = csrc[e];
        float a = alpha[(size_t)e * 8 + hh];
        ushort4 u4 = *(const ushort4*)(h + (size_t)s * 256 + ch);
        acc[0] += a * b2f(u4.x); acc[1] += a * b2f(u4.y);
        acc[2] += a * b2f(u4.z); acc[3] += a * b2f(u4.w);
    }
    *(float4*)&sh[ch] = make_float4(acc[0], acc[1], acc[2], acc[3]);
    __syncthreads();
    if (tid < 32) {
        float v1 = (sh[tid] + sh[tid + 32] + sh[tid + 64] + sh[tid + 96]) * 0.25f + b1[tid];
        float v2 = (sh[tid + 128] + sh[tid + 160] + sh[tid + 192] + sh[tid + 224]) * 0.25f
                   + b2[tid];
        out1[(size_t)n * 32 + tid] = v1;
        out2[(size_t)n * 32 + tid] = v2;
    }
}

// ---------------- orchestration ----------------

extern "C" void kernel_launch(void* const* d_in, const int* in_sizes, int n_in,
                              void* d_out, int out_size, void* d_ws, size_t ws_size,
                              hipStream_t stream) {
    (void)n_in; (void)out_size; (void)ws_size;
    const float* x   = (const float*)d_in[0];
    const int*   ei  = (const int*)d_in[1];
    const float* W1  = (const float*)d_in[2];
    const float* as1 = (const float*)d_in[3];
    const float* ad1 = (const float*)d_in[4];
    const float* b1  = (const float*)d_in[5];
    const float* W2  = (const float*)d_in[6];
    const float* as2 = (const float*)d_in[7];
    const float* ad2 = (const float*)d_in[8];
    const float* b2  = (const float*)d_in[9];
    const float* Wm  = (const float*)d_in[10];
    const float* a_sm = (const float*)d_in[11];
    const float* a_dm = (const float*)d_in[12];
    const float* bm  = (const float*)d_in[13];
    const float* Wl  = (const float*)d_in[14];
    const float* a_sl = (const float*)d_in[15];
    const float* a_dl = (const float*)d_in[16];
    const float* bl  = (const float*)d_in[17];
    float* outp = (float*)d_out;

    const int N  = in_sizes[0] / 256;   // 30000
    const int E  = in_sizes[1] / 2;     // 480000
    const int ET = E + N;               // with self loops
    const int gM = (N + 127) / 128;     // 235
    const int Mp = gM * 128;            // 30080

    auto align_up = [](size_t v) { return (v + 255) & ~(size_t)255; };
    char* w = (char*)d_ws;
    int* row_ptr = (int*)w;  w += align_up((size_t)(N + 1) * 4);
    int* cnt     = (int*)w;  w += align_up((size_t)N * 4);
    int* csrc    = (int*)w;  w += align_up((size_t)ET * 4);
    float* al_s  = (float*)w; w += align_up((size_t)N * 8 * 4);
    float* al_d  = (float*)w; w += align_up((size_t)N * 8 * 4);
    float* alpha = (float*)w; w += align_up((size_t)ET * 8 * 4);
    unsigned short* xb   = (unsigned short*)w; w += align_up((size_t)Mp * 256 * 2);
    unsigned short* W1t  = (unsigned short*)w; w += align_up((size_t)256 * 256 * 2);
    unsigned short* W2t  = (unsigned short*)w; w += align_up((size_t)512 * 256 * 2);
    unsigned short* WmlT = (unsigned short*)w; w += align_up((size_t)256 * 512 * 2);
    unsigned short* bufH = (unsigned short*)w; w += align_up((size_t)N * 512 * 2);
    unsigned short* bufO = (unsigned short*)w; w += align_up((size_t)Mp * 512 * 2);

    // ---- CSR build ----
    int gzN = (N + 255) / 256;
    int gzE = (ET + 255) / 256;
    zero_int_kernel<<<gzN, 256, 0, stream>>>(cnt, N);
    count_edges_kernel<<<gzE, 256, 0, stream>>>(ei, E, N, cnt);
    scan_kernel<<<1, 1024, 0, stream>>>(cnt, row_ptr, N);
    zero_int_kernel<<<gzN, 256, 0, stream>>>(cnt, N);
    scatter_edges_kernel<<<gzE, 256, 0, stream>>>(ei, E, N, row_ptr, cnt, csrc);

    // ---- dtype prep ----
    f32_to_bf16_pad4_kernel<<<((Mp * 256 / 4) + 255) / 256, 256, 0, stream>>>(
        x, xb, N, 256, Mp);
    transpose_w_kernel<<<(256 * 256 + 255) / 256, 256, 0, stream>>>(W1, W1t, 256, 256);
    transpose_w_kernel<<<(256 * 512 + 255) / 256, 256, 0, stream>>>(W2, W2t, 256, 512);
    transpose_w_kernel<<<(512 * 128 + 255) / 256, 256, 0, stream>>>(Wm, WmlT, 512, 128);
    transpose_w_kernel<<<(512 * 128 + 255) / 256, 256, 0, stream>>>(
        Wl, WmlT + (size_t)128 * 512, 512, 128);

    int gStat = (N + 255) / 256;

    // ---- Layer 1: GAT(256 -> 4x64, concat) + ReLU ----
    gemm_bf16_kernel<<<dim3(2, gM), 256, 0, stream>>>(xb, W1t, bufH, N, 256, 256);
    al_kernel<<<(N * 4 + 3) / 4, 256, 0, stream>>>(bufH, as1, ad1, as1, ad1,
                                                   al_s, al_d, N * 4, 256, 64, 4);
    stats_alpha_kernel<1><<<gStat, 256, 0, stream>>>(row_ptr, csrc, al_s, al_d, alpha, N);
    agg_concat_kernel<4, 4><<<N, 64, 0, stream>>>(row_ptr, csrc, alpha, bufH, b1,
                                                  bufO, 256, 64);

    // ---- Layer 2: GAT(256 -> 4x128, concat) + ReLU ----
    gemm_bf16_kernel<<<dim3(4, gM), 256, 0, stream>>>(bufO, W2t, bufH, N, 256, 512);
    al_kernel<<<(N * 4 + 3) / 4, 256, 0, stream>>>(bufH, as2, ad2, as2, ad2,
                                                   al_s, al_d, N * 4, 512, 128, 4);
    stats_alpha_kernel<1><<<gStat, 256, 0, stream>>>(row_ptr, csrc, al_s, al_d, alpha, N);
    agg_concat_kernel<8, 4><<<N, 64, 0, stream>>>(row_ptr, csrc, alpha, bufH, b2,
                                                  bufO, 512, 128);

    // ---- Layers 3+4 batched: GAT(512 -> 8x32, mean per 4-head group) ----
    gemm_bf16_kernel<<<dim3(2, gM), 256, 0, stream>>>(bufO, WmlT, bufH, N, 512, 256);
    al_kernel<<<(N * 8 + 7) / 8, 256, 0, stream>>>(bufH, a_sm, a_dm, a_sl, a_dl,
                                                   al_s, al_d, N * 8, 256, 32, 8);
    stats_alpha_kernel<2><<<gStat, 256, 0, stream>>>(row_ptr, csrc, al_s, al_d, alpha, N);
    agg_mean2_kernel<<<N, 64, 0, stream>>>(row_ptr, csrc, alpha, bufH, bm, bl,
                                           outp, outp + (size_t)N * 32);
}

// Round 5
// 532.771 us; speedup vs baseline: 2.2813x; 1.1614x over previous
//
#include <hip/hip_runtime.h>
#include <cstddef>

typedef __attribute__((ext_vector_type(8))) short short8;
typedef __attribute__((ext_vector_type(4))) float f32x4;

__device__ __forceinline__ float b2f(unsigned short u) {
    union { unsigned int i; float f; } x; x.i = ((unsigned int)u) << 16; return x.f;
}
__device__ __forceinline__ unsigned short f2b(float f) {
    union { float f; unsigned int i; } x; x.f = f;
    unsigned int r = x.i + 0x7FFF + ((x.i >> 16) & 1);
    return (unsigned short)(r >> 16);
}
__device__ __forceinline__ float lrelu(float v) { return v > 0.f ? v : 0.2f * v; }

// ---------------- CSR build ----------------

__global__ void zero_int_kernel(int* __restrict__ p, int n) {
    int i = blockIdx.x * blockDim.x + threadIdx.x;
    if (i < n) p[i] = 0;
}

__global__ void count_edges_kernel(const int* __restrict__ ei, int E, int N,
                                   int* __restrict__ cnt) {
    int e = blockIdx.x * blockDim.x + threadIdx.x;
    if (e >= E + N) return;
    int d = (e < E) ? ei[E + e] : (e - E);  // self loops appended
    atomicAdd(&cnt[d], 1);
}

// single block, 1024 threads; per-thread serial chunk + one block scan
__global__ void scan_kernel(const int* __restrict__ cnt, int* __restrict__ rp, int n) {
    __shared__ int sh[1024];
    int t = threadIdx.x;
    int chunk = (n + 1023) >> 10;
    int beg = t * chunk;
    int end = beg + chunk < n ? beg + chunk : n;
    int local = 0;
    for (int i = beg; i < end; i++) local += cnt[i];
    sh[t] = local;
    __syncthreads();
    for (int off = 1; off < 1024; off <<= 1) {
        int v = (t >= off) ? sh[t - off] : 0;
        __syncthreads();
        sh[t] += v;
        __syncthreads();
    }
    int run = (t == 0) ? 0 : sh[t - 1];
    for (int i = beg; i < end; i++) { run += cnt[i]; rp[i + 1] = run; }
    if (t == 0) rp[0] = 0;
}

__global__ void scatter_edges_kernel(const int* __restrict__ ei, int E, int N,
                                     const int* __restrict__ rp, int* __restrict__ cur,
                                     int* __restrict__ csrc) {
    int e = blockIdx.x * blockDim.x + threadIdx.x;
    if (e >= E + N) return;
    int s, d;
    if (e < E) { s = ei[e]; d = ei[E + e]; } else { s = e - E; d = s; }
    int pos = rp[d] + atomicAdd(&cur[d], 1);
    csrc[pos] = s;
}

// ---------------- dtype prep ----------------

__global__ void f32_to_bf16_pad4_kernel(const float* __restrict__ in,
                                        unsigned short* __restrict__ out,
                                        int rows, int cols, int padRows) {
    int i = blockIdx.x * blockDim.x + threadIdx.x;
    int total = (padRows * cols) >> 2;
    if (i >= total) return;
    int r = (i * 4) / cols;
    ushort4 o;
    if (r < rows) {
        float4 v = *(const float4*)(in + (size_t)i * 4);
        o = make_ushort4(f2b(v.x), f2b(v.y), f2b(v.z), f2b(v.w));
    } else {
        o = make_ushort4(0, 0, 0, 0);
    }
    *(ushort4*)(out + (size_t)i * 4) = o;
}

// W f32 [K, Nc] -> Wt bf16 [Nc, K]
__global__ void transpose_w_kernel(const float* __restrict__ W,
                                   unsigned short* __restrict__ Wt, int K, int Nc) {
    int i = blockIdx.x * blockDim.x + threadIdx.x;
    if (i >= K * Nc) return;
    int k = i / Nc, n = i - k * Nc;
    Wt[(size_t)n * K + k] = f2b(W[i]);
}

// ---------------- bf16 MFMA GEMM: C[M,Nc] = A[Mp,K] @ Bt[Nc,K]^T ----------------
// 128x128 tile, BK=32, 256 threads (4 waves in 2x2), mfma_f32_16x16x32_bf16.

__global__ __launch_bounds__(256) void gemm_bf16_kernel(
    const unsigned short* __restrict__ A, const unsigned short* __restrict__ Bt,
    unsigned short* __restrict__ C, int M, int K, int Nc) {
    __shared__ short As[128 * 32];
    __shared__ short Bs[128 * 32];
    int tid = threadIdx.x;
    int bm = blockIdx.y * 128;
    int bn = blockIdx.x * 128;
    int wave = tid >> 6, lane = tid & 63;
    int wm = (wave >> 1) * 64, wn = (wave & 1) * 64;
    int lm = lane & 15, lq = lane >> 4;

    f32x4 acc[4][4] = {};

    int c0 = tid, c1 = tid + 256;
    const unsigned short* Ap0 = A + (size_t)(bm + (c0 >> 2)) * K + (c0 & 3) * 8;
    const unsigned short* Ap1 = A + (size_t)(bm + (c1 >> 2)) * K + (c1 & 3) * 8;
    const unsigned short* Bp0 = Bt + (size_t)(bn + (c0 >> 2)) * K + (c0 & 3) * 8;
    const unsigned short* Bp1 = Bt + (size_t)(bn + (c1 >> 2)) * K + (c1 & 3) * 8;

    for (int kk = 0; kk < K; kk += 32) {
        short8 a0 = *(const short8*)(Ap0 + kk);
        short8 a1 = *(const short8*)(Ap1 + kk);
        short8 b0 = *(const short8*)(Bp0 + kk);
        short8 b1 = *(const short8*)(Bp1 + kk);
        __syncthreads();
        *(short8*)&As[c0 * 8] = a0;
        *(short8*)&As[c1 * 8] = a1;
        *(short8*)&Bs[c0 * 8] = b0;
        *(short8*)&Bs[c1 * 8] = b1;
        __syncthreads();
        short8 af[4], bf[4];
#pragma unroll
        for (int t = 0; t < 4; t++) {
            af[t] = *(const short8*)&As[(wm + t * 16 + lm) * 32 + lq * 8];
            bf[t] = *(const short8*)&Bs[(wn + t * 16 + lm) * 32 + lq * 8];
        }
#pragma unroll
        for (int tm = 0; tm < 4; tm++)
#pragma unroll
            for (int tn = 0; tn < 4; tn++)
                acc[tm][tn] = __builtin_amdgcn_mfma_f32_16x16x32_bf16(
                    af[tm], bf[tn], acc[tm][tn], 0, 0, 0);
    }
#pragma unroll
    for (int tm = 0; tm < 4; tm++) {
#pragma unroll
        for (int r = 0; r < 4; r++) {
            int row = bm + wm + tm * 16 + lq * 4 + r;
            if (row < M) {
#pragma unroll
                for (int tn = 0; tn < 4; tn++) {
                    int col = bn + wn + tn * 16 + lm;
                    C[(size_t)row * Nc + col] = f2b(acc[tm][tn][r]);
                }
            }
        }
    }
}

// ---------------- attention logits (H heads, hi pointers for heads 4..7) ----------------

__global__ __launch_bounds__(256) void al_kernel(
    const unsigned short* __restrict__ h,
    const float* __restrict__ aslo, const float* __restrict__ adlo,
    const float* __restrict__ ashi, const float* __restrict__ adhi,
    float* __restrict__ al_s, float* __restrict__ al_d,
    int NHtot, int HC, int C, int H) {
    int lane = threadIdx.x & 63;
    int wv = blockIdx.x * 4 + (threadIdx.x >> 6);
    if (C >= 64) {
        if (wv >= NHtot) return;
        int n = wv / H, hh = wv % H;
        const float* as_ = (hh < 4) ? (aslo + hh * C) : (ashi + (hh - 4) * C);
        const float* ad_ = (hh < 4) ? (adlo + hh * C) : (adhi + (hh - 4) * C);
        const unsigned short* row = h + (size_t)n * HC + hh * C;
        float s1 = 0.f, s2 = 0.f;
        for (int c = lane; c < C; c += 64) {
            float v = b2f(row[c]);
            s1 += v * as_[c];
            s2 += v * ad_[c];
        }
#pragma unroll
        for (int off = 32; off > 0; off >>= 1) {
            s1 += __shfl_down(s1, off);
            s2 += __shfl_down(s2, off);
        }
        if (lane == 0) { al_s[wv] = s1; al_d[wv] = s2; }
    } else {  // C == 32: two (n,head) pairs per wave
        int wid = wv * 2 + (lane >> 5);
        int widc = wid < NHtot ? wid : NHtot - 1;
        int n = widc / H, hh = widc % H;
        const float* as_ = (hh < 4) ? (aslo + hh * C) : (ashi + (hh - 4) * C);
        const float* ad_ = (hh < 4) ? (adlo + hh * C) : (adhi + (hh - 4) * C);
        int c = lane & 31;
        float v = b2f(h[(size_t)n * HC + hh * C + c]);
        float s1 = v * as_[c], s2 = v * ad_[c];
#pragma unroll
        for (int off = 16; off > 0; off >>= 1) {
            s1 += __shfl_down(s1, off);
            s2 += __shfl_down(s2, off);
        }
        if ((lane & 31) == 0 && wid < NHtot) { al_s[wid] = s1; al_d[wid] = s2; }
    }
}

// ---------------- wave-per-node fused softmax stats + alpha ----------------
// One 64-lane wave per dst node. Lane e handles edge beg+e (loop if deg>64).
// Butterfly shuffle reductions for max and expsum; each lane writes its
// normalized alpha once. H = 4*H4 heads.

template <int H4>
__global__ __launch_bounds__(64) void stats_alpha_kernel(
    const int* __restrict__ rp, const int* __restrict__ csrc,
    const float* __restrict__ al_s, const float* __restrict__ al_d,
    float* __restrict__ alpha, int N) {
    const int H = 4 * H4;
    int n = blockIdx.x;
    int lane = threadIdx.x;
    int beg = rp[n], end = rp[n + 1];
    int deg = end - beg;
    if (deg <= 0) return;
    float ad[4 * H4];
#pragma unroll
    for (int g = 0; g < H4; g++)
        *(float4*)&ad[g * 4] = *(const float4*)(al_d + (size_t)n * H + g * 4);

    if (deg <= 64) {
        bool act = lane < deg;
        int e = beg + (act ? lane : 0);
        int s = csrc[e];
        float v[4 * H4];
#pragma unroll
        for (int g = 0; g < H4; g++) {
            float4 as = *(const float4*)(al_s + (size_t)s * H + g * 4);
            v[g * 4 + 0] = lrelu(as.x + ad[g * 4 + 0]);
            v[g * 4 + 1] = lrelu(as.y + ad[g * 4 + 1]);
            v[g * 4 + 2] = lrelu(as.z + ad[g * 4 + 2]);
            v[g * 4 + 3] = lrelu(as.w + ad[g * 4 + 3]);
        }
        float m[4 * H4];
#pragma unroll
        for (int j = 0; j < 4 * H4; j++) m[j] = act ? v[j] : -3.402823466e38f;
#pragma unroll
        for (int off = 32; off >= 1; off >>= 1)
#pragma unroll
            for (int j = 0; j < 4 * H4; j++)
                m[j] = fmaxf(m[j], __shfl_xor(m[j], off));
        float ex[4 * H4];
#pragma unroll
        for (int j = 0; j < 4 * H4; j++) ex[j] = act ? __expf(v[j] - m[j]) : 0.f;
        float sum[4 * H4];
#pragma unroll
        for (int j = 0; j < 4 * H4; j++) sum[j] = ex[j];
#pragma unroll
        for (int off = 32; off >= 1; off >>= 1)
#pragma unroll
            for (int j = 0; j < 4 * H4; j++)
                sum[j] += __shfl_xor(sum[j], off);
        if (act) {
#pragma unroll
            for (int g = 0; g < H4; g++) {
                float4 o;
                o.x = ex[g * 4 + 0] / (sum[g * 4 + 0] + 1e-16f);
                o.y = ex[g * 4 + 1] / (sum[g * 4 + 1] + 1e-16f);
                o.z = ex[g * 4 + 2] / (sum[g * 4 + 2] + 1e-16f);
                o.w = ex[g * 4 + 3] / (sum[g * 4 + 3] + 1e-16f);
                *(float4*)(alpha + (size_t)e * H + g * 4) = o;
            }
        }
    } else {
        // general path (deg > 64): three strided loops
        float m[4 * H4];
#pragma unroll
        for (int j = 0; j < 4 * H4; j++) m[j] = -3.402823466e38f;
        for (int e = beg + lane; e < end; e += 64) {
            int s = csrc[e];
#pragma unroll
            for (int g = 0; g < H4; g++) {
                float4 as = *(const float4*)(al_s + (size_t)s * H + g * 4);
                m[g * 4 + 0] = fmaxf(m[g * 4 + 0], lrelu(as.x + ad[g * 4 + 0]));
                m[g * 4 + 1] = fmaxf(m[g * 4 + 1], lrelu(as.y + ad[g * 4 + 1]));
                m[g * 4 + 2] = fmaxf(m[g * 4 + 2], lrelu(as.z + ad[g * 4 + 2]));
                m[g * 4 + 3] = fmaxf(m[g * 4 + 3], lrelu(as.w + ad[g * 4 + 3]));
            }
        }
#pragma unroll
        for (int off = 32; off >= 1; off >>= 1)
#pragma unroll
            for (int j = 0; j < 4 * H4; j++)
                m[j] = fmaxf(m[j], __shfl_xor(m[j], off));
        float sum[4 * H4];
#pragma unroll
        for (int j = 0; j < 4 * H4; j++) sum[j] = 0.f;
        for (int e = beg + lane; e < end; e += 64) {
            int s = csrc[e];
#pragma unroll
            for (int g = 0; g < H4; g++) {
                float4 as = *(const float4*)(al_s + (size_t)s * H + g * 4);
                float4 exv;
                exv.x = __expf(lrelu(as.x + ad[g * 4 + 0]) - m[g * 4 + 0]);
                exv.y = __expf(lrelu(as.y + ad[g * 4 + 1]) - m[g * 4 + 1]);
                exv.z = __expf(lrelu(as.z + ad[g * 4 + 2]) - m[g * 4 + 2]);
                exv.w = __expf(lrelu(as.w + ad[g * 4 + 3]) - m[g * 4 + 3]);
                sum[g * 4 + 0] += exv.x; sum[g * 4 + 1] += exv.y;
                sum[g * 4 + 2] += exv.z; sum[g * 4 + 3] += exv.w;
                *(float4*)(alpha + (size_t)e * H + g * 4) = exv;
            }
        }
#pragma unroll
        for (int off = 32; off >= 1; off >>= 1)
#pragma unroll
            for (int j = 0; j < 4 * H4; j++)
                sum[j] += __shfl_xor(sum[j], off);
        float r[4 * H4];
#pragma unroll
        for (int j = 0; j < 4 * H4; j++) r[j] = 1.0f / (sum[j] + 1e-16f);
        for (int e = beg + lane; e < end; e += 64) {
#pragma unroll
            for (int g = 0; g < H4; g++) {
                float4 a = *(const float4*)(alpha + (size_t)e * H + g * 4);
                a.x *= r[g * 4 + 0]; a.y *= r[g * 4 + 1];
                a.z *= r[g * 4 + 2]; a.w *= r[g * 4 + 3];
                *(float4*)(alpha + (size_t)e * H + g * 4) = a;
            }
        }
    }
}

// ---------------- aggregate (concat layers): block(64) per dst node ----------------

template <int V, int H>
__global__ void agg_concat_kernel(
    const int* __restrict__ rp, const int* __restrict__ csrc,
    const float* __restrict__ alpha, const unsigned short* __restrict__ h,
    const float* __restrict__ bias, unsigned short* __restrict__ out,
    int HC, int C) {
    int n = blockIdx.x, tid = threadIdx.x;
    int ch = tid * V;
    int hh = ch / C;
    int beg = rp[n], end = rp[n + 1];
    float acc[V];
#pragma unroll
    for (int j = 0; j < V; j++) acc[j] = 0.f;
    int e = beg;
    for (; e + 4 <= end; e += 4) {
#pragma unroll
        for (int u = 0; u < 4; u++) {
            int s = csrc[e + u];
            float a = alpha[(size_t)(e + u) * H + hh];
            const unsigned short* p = h + (size_t)s * HC + ch;
            if constexpr (V == 8) {
                short8 uv = *(const short8*)p;
#pragma unroll
                for (int j = 0; j < 8; j++) acc[j] += a * b2f((unsigned short)uv[j]);
            } else {
                ushort4 u4 = *(const ushort4*)p;
                acc[0] += a * b2f(u4.x); acc[1] += a * b2f(u4.y);
                acc[2] += a * b2f(u4.z); acc[3] += a * b2f(u4.w);
            }
        }
    }
    for (; e < end; e++) {
        int s = csrc[e];
        float a = alpha[(size_t)e * H + hh];
        const unsigned short* p = h + (size_t)s * HC + ch;
        if constexpr (V == 8) {
            short8 uv = *(const short8*)p;
#pragma unroll
            for (int j = 0; j < 8; j++) acc[j] += a * b2f((unsigned short)uv[j]);
        } else {
            ushort4 u4 = *(const ushort4*)p;
            acc[0] += a * b2f(u4.x); acc[1] += a * b2f(u4.y);
            acc[2] += a * b2f(u4.z); acc[3] += a * b2f(u4.w);
        }
    }
    if constexpr (V == 8) {
        short8 o;
#pragma unroll
        for (int j = 0; j < 8; j++)
            o[j] = (short)f2b(fmaxf(acc[j] + bias[ch + j], 0.f));
        *(short8*)(out + (size_t)n * HC + ch) = o;
    } else {
        ushort4 o;
        o.x = f2b(fmaxf(acc[0] + bias[ch + 0], 0.f));
        o.y = f2b(fmaxf(acc[1] + bias[ch + 1], 0.f));
        o.z = f2b(fmaxf(acc[2] + bias[ch + 2], 0.f));
        o.w = f2b(fmaxf(acc[3] + bias[ch + 3], 0.f));
        *(ushort4*)(out + (size_t)n * HC + ch) = o;
    }
}

// ---------------- aggregate (batched L3+L4, 8 heads x 32ch, mean over head groups) ----------------

__global__ void agg_mean2_kernel(
    const int* __restrict__ rp, const int* __restrict__ csrc,
    const float* __restrict__ alpha, const unsigned short* __restrict__ h,
    const float* __restrict__ b1, const float* __restrict__ b2,
    float* __restrict__ out1, float* __restrict__ out2) {
    __shared__ float sh[256];
    int n = blockIdx.x, tid = threadIdx.x;
    int ch = tid * 4;
    int hh = ch >> 5;
    int beg = rp[n], end = rp[n + 1];
    float acc[4] = {0.f, 0.f, 0.f, 0.f};
    int e = beg;
    for (; e + 4 <= end; e += 4) {
#pragma unroll
        for (int u = 0; u < 4; u++) {
            int s = csrc[e + u];
            float a = alpha[(size_t)(e + u) * 8 + hh];
            ushort4 u4 = *(const ushort4*)(h + (size_t)s * 256 + ch);
            acc[0] += a * b2f(u4.x); acc[1] += a * b2f(u4.y);
            acc[2] += a * b2f(u4.z); acc[3] += a * b2f(u4.w);
        }
    }
    for (; e < end; e++) {
        int s = csrc[e];
        float a = alpha[(size_t)e * 8 + hh];
        ushort4 u4 = *(const ushort4*)(h + (size_t)s * 256 + ch);
        acc[0] += a * b2f(u4.x); acc[1] += a * b2f(u4.y);
        acc[2] += a * b2f(u4.z); acc[3] += a * b2f(u4.w);
    }
    *(float4*)&sh[ch] = make_float4(acc[0], acc[1], acc[2], acc[3]);
    __syncthreads();
    if (tid < 32) {
        float v1 = (sh[tid] + sh[tid + 32] + sh[tid + 64] + sh[tid + 96]) * 0.25f + b1[tid];
        float v2 = (sh[tid + 128] + sh[tid + 160] + sh[tid + 192] + sh[tid + 224]) * 0.25f
                   + b2[tid];
        out1[(size_t)n * 32 + tid] = v1;
        out2[(size_t)n * 32 + tid] = v2;
    }
}

// ---------------- orchestration ----------------

extern "C" void kernel_launch(void* const* d_in, const int* in_sizes, int n_in,
                              void* d_out, int out_size, void* d_ws, size_t ws_size,
                              hipStream_t stream) {
    (void)n_in; (void)out_size; (void)ws_size;
    const float* x   = (const float*)d_in[0];
    const int*   ei  = (const int*)d_in[1];
    const float* W1  = (const float*)d_in[2];
    const float* as1 = (const float*)d_in[3];
    const float* ad1 = (const float*)d_in[4];
    const float* b1  = (const float*)d_in[5];
    const float* W2  = (const float*)d_in[6];
    const float* as2 = (const float*)d_in[7];
    const float* ad2 = (const float*)d_in[8];
    const float* b2  = (const float*)d_in[9];
    const float* Wm  = (const float*)d_in[10];
    const float* a_sm = (const float*)d_in[11];
    const float* a_dm = (const float*)d_in[12];
    const float* bm  = (const float*)d_in[13];
    const float* Wl  = (const float*)d_in[14];
    const float* a_sl = (const float*)d_in[15];
    const float* a_dl = (const float*)d_in[16];
    const float* bl  = (const float*)d_in[17];
    float* outp = (float*)d_out;

    const int N  = in_sizes[0] / 256;   // 30000
    const int E  = in_sizes[1] / 2;     // 480000
    const int ET = E + N;               // with self loops
    const int gM = (N + 127) / 128;     // 235
    const int Mp = gM * 128;            // 30080

    auto align_up = [](size_t v) { return (v + 255) & ~(size_t)255; };
    char* w = (char*)d_ws;
    int* row_ptr = (int*)w;  w += align_up((size_t)(N + 1) * 4);
    int* cnt     = (int*)w;  w += align_up((size_t)N * 4);
    int* csrc    = (int*)w;  w += align_up((size_t)ET * 4);
    float* al_s  = (float*)w; w += align_up((size_t)N * 8 * 4);
    float* al_d  = (float*)w; w += align_up((size_t)N * 8 * 4);
    float* alpha = (float*)w; w += align_up((size_t)ET * 8 * 4);
    unsigned short* xb   = (unsigned short*)w; w += align_up((size_t)Mp * 256 * 2);
    unsigned short* W1t  = (unsigned short*)w; w += align_up((size_t)256 * 256 * 2);
    unsigned short* W2t  = (unsigned short*)w; w += align_up((size_t)512 * 256 * 2);
    unsigned short* WmlT = (unsigned short*)w; w += align_up((size_t)256 * 512 * 2);
    unsigned short* bufH = (unsigned short*)w; w += align_up((size_t)N * 512 * 2);
    unsigned short* bufO = (unsigned short*)w; w += align_up((size_t)Mp * 512 * 2);

    // ---- CSR build ----
    int gzN = (N + 255) / 256;
    int gzE = (ET + 255) / 256;
    zero_int_kernel<<<gzN, 256, 0, stream>>>(cnt, N);
    count_edges_kernel<<<gzE, 256, 0, stream>>>(ei, E, N, cnt);
    scan_kernel<<<1, 1024, 0, stream>>>(cnt, row_ptr, N);
    zero_int_kernel<<<gzN, 256, 0, stream>>>(cnt, N);
    scatter_edges_kernel<<<gzE, 256, 0, stream>>>(ei, E, N, row_ptr, cnt, csrc);

    // ---- dtype prep ----
    f32_to_bf16_pad4_kernel<<<((Mp * 256 / 4) + 255) / 256, 256, 0, stream>>>(
        x, xb, N, 256, Mp);
    transpose_w_kernel<<<(256 * 256 + 255) / 256, 256, 0, stream>>>(W1, W1t, 256, 256);
    transpose_w_kernel<<<(256 * 512 + 255) / 256, 256, 0, stream>>>(W2, W2t, 256, 512);
    transpose_w_kernel<<<(512 * 128 + 255) / 256, 256, 0, stream>>>(Wm, WmlT, 512, 128);
    transpose_w_kernel<<<(512 * 128 + 255) / 256, 256, 0, stream>>>(
        Wl, WmlT + (size_t)128 * 512, 512, 128);

    // ---- Layer 1: GAT(256 -> 4x64, concat) + ReLU ----
    gemm_bf16_kernel<<<dim3(2, gM), 256, 0, stream>>>(xb, W1t, bufH, N, 256, 256);
    al_kernel<<<(N * 4 + 3) / 4, 256, 0, stream>>>(bufH, as1, ad1, as1, ad1,
                                                   al_s, al_d, N * 4, 256, 64, 4);
    stats_alpha_kernel<1><<<N, 64, 0, stream>>>(row_ptr, csrc, al_s, al_d, alpha, N);
    agg_concat_kernel<4, 4><<<N, 64, 0, stream>>>(row_ptr, csrc, alpha, bufH, b1,
                                                  bufO, 256, 64);

    // ---- Layer 2: GAT(256 -> 4x128, concat) + ReLU ----
    gemm_bf16_kernel<<<dim3(4, gM), 256, 0, stream>>>(bufO, W2t, bufH, N, 256, 512);
    al_kernel<<<(N * 4 + 3) / 4, 256, 0, stream>>>(bufH, as2, ad2, as2, ad2,
                                                   al_s, al_d, N * 4, 512, 128, 4);
    stats_alpha_kernel<1><<<N, 64, 0, stream>>>(row_ptr, csrc, al_s, al_d, alpha, N);
    agg_concat_kernel<8, 4><<<N, 64, 0, stream>>>(row_ptr, csrc, alpha, bufH, b2,
                                                  bufO, 512, 128);

    // ---- Layers 3+4 batched: GAT(512 -> 8x32, mean per 4-head group) ----
    gemm_bf16_kernel<<<dim3(2, gM), 256, 0, stream>>>(bufO, WmlT, bufH, N, 512, 256);
    al_kernel<<<(N * 8 + 7) / 8, 256, 0, stream>>>(bufH, a_sm, a_dm, a_sl, a_dl,
                                                   al_s, al_d, N * 8, 256, 32, 8);
    stats_alpha_kernel<2><<<N, 64, 0, stream>>>(row_ptr, csrc, al_s, al_d, alpha, N);
    agg_mean2_kernel<<<N, 64, 0, stream>>>(row_ptr, csrc, alpha, bufH, bm, bl,
                                           outp, outp + (size_t)N * 32);
}

// Round 6
// 482.564 us; speedup vs baseline: 2.5187x; 1.1040x over previous
//
#include <hip/hip_runtime.h>
#include <cstddef>

typedef __attribute__((ext_vector_type(8))) short short8;
typedef __attribute__((ext_vector_type(4))) float f32x4;

__device__ __forceinline__ float b2f(unsigned short u) {
    union { unsigned int i; float f; } x; x.i = ((unsigned int)u) << 16; return x.f;
}
__device__ __forceinline__ unsigned short f2b(float f) {
    union { float f; unsigned int i; } x; x.f = f;
    unsigned int r = x.i + 0x7FFF + ((x.i >> 16) & 1);
    return (unsigned short)(r >> 16);
}
__device__ __forceinline__ float lrelu(float v) { return v > 0.f ? v : 0.2f * v; }

// ---------------- CSR build ----------------

__global__ void count_edges_kernel(const int* __restrict__ ei, int E, int N,
                                   int* __restrict__ cnt) {
    int e = blockIdx.x * blockDim.x + threadIdx.x;
    if (e >= E + N) return;
    int d = (e < E) ? ei[E + e] : (e - E);  // self loops appended
    atomicAdd(&cnt[d], 1);
}

// single block, 1024 threads; per-thread serial chunk + one block scan.
// Also re-zeroes cnt for use as the scatter cursor.
__global__ void scan_kernel(int* __restrict__ cnt, int* __restrict__ rp, int n) {
    __shared__ int sh[1024];
    int t = threadIdx.x;
    int chunk = (n + 1023) >> 10;
    int beg = t * chunk;
    int end = beg + chunk < n ? beg + chunk : n;
    int local = 0;
    for (int i = beg; i < end; i++) local += cnt[i];
    sh[t] = local;
    __syncthreads();
    for (int off = 1; off < 1024; off <<= 1) {
        int v = (t >= off) ? sh[t - off] : 0;
        __syncthreads();
        sh[t] += v;
        __syncthreads();
    }
    int run = (t == 0) ? 0 : sh[t - 1];
    for (int i = beg; i < end; i++) {
        int c = cnt[i];
        cnt[i] = 0;
        run += c;
        rp[i + 1] = run;
    }
    if (t == 0) rp[0] = 0;
}

__global__ void scatter_edges_kernel(const int* __restrict__ ei, int E, int N,
                                     const int* __restrict__ rp, int* __restrict__ cur,
                                     int* __restrict__ csrc) {
    int e = blockIdx.x * blockDim.x + threadIdx.x;
    if (e >= E + N) return;
    int s, d;
    if (e < E) { s = ei[e]; d = ei[E + e]; } else { s = e - E; d = s; }
    int pos = rp[d] + atomicAdd(&cur[d], 1);
    csrc[pos] = s;
}

// ---------------- dtype prep ----------------

__global__ void f32_to_bf16_pad4_kernel(const float* __restrict__ in,
                                        unsigned short* __restrict__ out,
                                        int rows, int cols, int padRows) {
    int i = blockIdx.x * blockDim.x + threadIdx.x;
    int total = (padRows * cols) >> 2;
    if (i >= total) return;
    int r = (i * 4) / cols;
    ushort4 o;
    if (r < rows) {
        float4 v = *(const float4*)(in + (size_t)i * 4);
        o = make_ushort4(f2b(v.x), f2b(v.y), f2b(v.z), f2b(v.w));
    } else {
        o = make_ushort4(0, 0, 0, 0);
    }
    *(ushort4*)(out + (size_t)i * 4) = o;
}

// All four weight transposes in one launch.
// W1[256,256]->W1t[256,256]; W2[256,512]->W2t[512,256];
// Wm[512,128]->WmlT[0..128); Wl[512,128]->WmlT[128..256) (both [.,512]).
__global__ void transpose_all_kernel(
    const float* __restrict__ W1, const float* __restrict__ W2,
    const float* __restrict__ Wm, const float* __restrict__ Wl,
    unsigned short* __restrict__ W1t, unsigned short* __restrict__ W2t,
    unsigned short* __restrict__ WmlT) {
    int i = blockIdx.x * blockDim.x + threadIdx.x;
    if (i < 65536) {
        int k = i >> 8, n = i & 255;
        W1t[(size_t)n * 256 + k] = f2b(W1[i]);
    } else if (i < 65536 + 131072) {
        int j = i - 65536;
        int k = j >> 9, n = j & 511;
        W2t[(size_t)n * 256 + k] = f2b(W2[j]);
    } else if (i < 65536 + 131072 + 65536) {
        int j = i - 196608;
        int k = j >> 7, n = j & 127;
        WmlT[(size_t)n * 512 + k] = f2b(Wm[j]);
    } else if (i < 65536 + 131072 + 131072) {
        int j = i - 262144;
        int k = j >> 7, n = j & 127;
        WmlT[(size_t)(128 + n) * 512 + k] = f2b(Wl[j]);
    }
}

// ---------------- bf16 MFMA GEMM: C[M,Nc] = A[Mp,K] @ Bt[Nc,K]^T ----------------
// 128x128 tile, BK=32, 256 threads (4 waves in 2x2), mfma_f32_16x16x32_bf16.

__global__ __launch_bounds__(256) void gemm_bf16_kernel(
    const unsigned short* __restrict__ A, const unsigned short* __restrict__ Bt,
    unsigned short* __restrict__ C, int M, int K, int Nc) {
    __shared__ short As[128 * 32];
    __shared__ short Bs[128 * 32];
    int tid = threadIdx.x;
    int bm = blockIdx.y * 128;
    int bn = blockIdx.x * 128;
    int wave = tid >> 6, lane = tid & 63;
    int wm = (wave >> 1) * 64, wn = (wave & 1) * 64;
    int lm = lane & 15, lq = lane >> 4;

    f32x4 acc[4][4] = {};

    int c0 = tid, c1 = tid + 256;
    const unsigned short* Ap0 = A + (size_t)(bm + (c0 >> 2)) * K + (c0 & 3) * 8;
    const unsigned short* Ap1 = A + (size_t)(bm + (c1 >> 2)) * K + (c1 & 3) * 8;
    const unsigned short* Bp0 = Bt + (size_t)(bn + (c0 >> 2)) * K + (c0 & 3) * 8;
    const unsigned short* Bp1 = Bt + (size_t)(bn + (c1 >> 2)) * K + (c1 & 3) * 8;

    for (int kk = 0; kk < K; kk += 32) {
        short8 a0 = *(const short8*)(Ap0 + kk);
        short8 a1 = *(const short8*)(Ap1 + kk);
        short8 b0 = *(const short8*)(Bp0 + kk);
        short8 b1 = *(const short8*)(Bp1 + kk);
        __syncthreads();
        *(short8*)&As[c0 * 8] = a0;
        *(short8*)&As[c1 * 8] = a1;
        *(short8*)&Bs[c0 * 8] = b0;
        *(short8*)&Bs[c1 * 8] = b1;
        __syncthreads();
        short8 af[4], bf[4];
#pragma unroll
        for (int t = 0; t < 4; t++) {
            af[t] = *(const short8*)&As[(wm + t * 16 + lm) * 32 + lq * 8];
            bf[t] = *(const short8*)&Bs[(wn + t * 16 + lm) * 32 + lq * 8];
        }
#pragma unroll
        for (int tm = 0; tm < 4; tm++)
#pragma unroll
            for (int tn = 0; tn < 4; tn++)
                acc[tm][tn] = __builtin_amdgcn_mfma_f32_16x16x32_bf16(
                    af[tm], bf[tn], acc[tm][tn], 0, 0, 0);
    }
#pragma unroll
    for (int tm = 0; tm < 4; tm++) {
#pragma unroll
        for (int r = 0; r < 4; r++) {
            int row = bm + wm + tm * 16 + lq * 4 + r;
            if (row < M) {
#pragma unroll
                for (int tn = 0; tn < 4; tn++) {
                    int col = bn + wn + tn * 16 + lm;
                    C[(size_t)row * Nc + col] = f2b(acc[tm][tn][r]);
                }
            }
        }
    }
}

// ---------------- attention logits (H heads, hi pointers for heads 4..7) ----------------

__global__ __launch_bounds__(256) void al_kernel(
    const unsigned short* __restrict__ h,
    const float* __restrict__ aslo, const float* __restrict__ adlo,
    const float* __restrict__ ashi, const float* __restrict__ adhi,
    float* __restrict__ al_s, float* __restrict__ al_d,
    int NHtot, int HC, int C, int H) {
    int lane = threadIdx.x & 63;
    int wv = blockIdx.x * 4 + (threadIdx.x >> 6);
    if (C >= 64) {
        if (wv >= NHtot) return;
        int n = wv / H, hh = wv % H;
        const float* as_ = (hh < 4) ? (aslo + hh * C) : (ashi + (hh - 4) * C);
        const float* ad_ = (hh < 4) ? (adlo + hh * C) : (adhi + (hh - 4) * C);
        const unsigned short* row = h + (size_t)n * HC + hh * C;
        float s1 = 0.f, s2 = 0.f;
        for (int c = lane; c < C; c += 64) {
            float v = b2f(row[c]);
            s1 += v * as_[c];
            s2 += v * ad_[c];
        }
#pragma unroll
        for (int off = 32; off > 0; off >>= 1) {
            s1 += __shfl_down(s1, off);
            s2 += __shfl_down(s2, off);
        }
        if (lane == 0) { al_s[wv] = s1; al_d[wv] = s2; }
    } else {  // C == 32: two (n,head) pairs per wave
        int wid = wv * 2 + (lane >> 5);
        int widc = wid < NHtot ? wid : NHtot - 1;
        int n = widc / H, hh = widc % H;
        const float* as_ = (hh < 4) ? (aslo + hh * C) : (ashi + (hh - 4) * C);
        const float* ad_ = (hh < 4) ? (adlo + hh * C) : (adhi + (hh - 4) * C);
        int c = lane & 31;
        float v = b2f(h[(size_t)n * HC + hh * C + c]);
        float s1 = v * as_[c], s2 = v * ad_[c];
#pragma unroll
        for (int off = 16; off > 0; off >>= 1) {
            s1 += __shfl_down(s1, off);
            s2 += __shfl_down(s2, off);
        }
        if ((lane & 31) == 0 && wid < NHtot) { al_s[wid] = s1; al_d[wid] = s2; }
    }
}

// ---------------- fully fused per-node edge kernel ----------------
// One 64-lane wave per dst node: segment softmax (lane-per-edge, butterfly
// reductions), alpha parked in LDS, then gather-aggregate (V channels/lane).
// H = 4*H4 heads. MODE 0: concat + bias + ReLU, bf16 out.
// MODE 1: two 4-head groups, head-mean + bias, f32 out1/out2 (HC=256, C=32).

template <int H4, int V, int MODE>
__global__ __launch_bounds__(64) void gat_fused_kernel(
    const int* __restrict__ rp, const int* __restrict__ csrc,
    const float* __restrict__ al_s, const float* __restrict__ al_d,
    const unsigned short* __restrict__ h,
    const float* __restrict__ bias1, const float* __restrict__ bias2,
    void* __restrict__ out1v, void* __restrict__ out2v, int HC, int C) {
    const int H = 4 * H4;
    __shared__ int lds_src[64];
    __shared__ float lds_alpha[64 * H];
    __shared__ float sh[256];
    int n = blockIdx.x;
    int lane = threadIdx.x;
    int beg = rp[n], end = rp[n + 1];
    int deg = end - beg;

    float ad[H];
#pragma unroll
    for (int g = 0; g < H4; g++)
        *(float4*)&ad[g * 4] = *(const float4*)(al_d + (size_t)n * H + g * 4);

    int ch = lane * V;
    int hh = ch / C;
    float acc[V];
#pragma unroll
    for (int j = 0; j < V; j++) acc[j] = 0.f;

    if (deg <= 64) {
        bool act = lane < deg;
        int s = act ? csrc[beg + lane] : 0;
        float v[H], m[H], ex[H], sum[H];
#pragma unroll
        for (int g = 0; g < H4; g++) {
            float4 as = *(const float4*)(al_s + (size_t)s * H + g * 4);
            v[g * 4 + 0] = lrelu(as.x + ad[g * 4 + 0]);
            v[g * 4 + 1] = lrelu(as.y + ad[g * 4 + 1]);
            v[g * 4 + 2] = lrelu(as.z + ad[g * 4 + 2]);
            v[g * 4 + 3] = lrelu(as.w + ad[g * 4 + 3]);
        }
#pragma unroll
        for (int j = 0; j < H; j++) m[j] = act ? v[j] : -3.402823466e38f;
#pragma unroll
        for (int off = 32; off >= 1; off >>= 1)
#pragma unroll
            for (int j = 0; j < H; j++) m[j] = fmaxf(m[j], __shfl_xor(m[j], off));
#pragma unroll
        for (int j = 0; j < H; j++) {
            ex[j] = act ? __expf(v[j] - m[j]) : 0.f;
            sum[j] = ex[j];
        }
#pragma unroll
        for (int off = 32; off >= 1; off >>= 1)
#pragma unroll
            for (int j = 0; j < H; j++) sum[j] += __shfl_xor(sum[j], off);
        if (act) {
            lds_src[lane] = s;
#pragma unroll
            for (int g = 0; g < H4; g++) {
                float4 o;
                o.x = ex[g * 4 + 0] / (sum[g * 4 + 0] + 1e-16f);
                o.y = ex[g * 4 + 1] / (sum[g * 4 + 1] + 1e-16f);
                o.z = ex[g * 4 + 2] / (sum[g * 4 + 2] + 1e-16f);
                o.w = ex[g * 4 + 3] / (sum[g * 4 + 3] + 1e-16f);
                *(float4*)&lds_alpha[lane * H + g * 4] = o;
            }
        }
        __syncthreads();
        int t = 0;
        for (; t + 4 <= deg; t += 4) {
#pragma unroll
            for (int u = 0; u < 4; u++) {
                int s2 = lds_src[t + u];
                float a = lds_alpha[(t + u) * H + hh];
                const unsigned short* p = h + (size_t)s2 * HC + ch;
                if constexpr (V == 8) {
                    short8 uv = *(const short8*)p;
#pragma unroll
                    for (int j = 0; j < 8; j++) acc[j] += a * b2f((unsigned short)uv[j]);
                } else {
                    ushort4 u4 = *(const ushort4*)p;
                    acc[0] += a * b2f(u4.x); acc[1] += a * b2f(u4.y);
                    acc[2] += a * b2f(u4.z); acc[3] += a * b2f(u4.w);
                }
            }
        }
        for (; t < deg; t++) {
            int s2 = lds_src[t];
            float a = lds_alpha[t * H + hh];
            const unsigned short* p = h + (size_t)s2 * HC + ch;
            if constexpr (V == 8) {
                short8 uv = *(const short8*)p;
#pragma unroll
                for (int j = 0; j < 8; j++) acc[j] += a * b2f((unsigned short)uv[j]);
            } else {
                ushort4 u4 = *(const ushort4*)p;
                acc[0] += a * b2f(u4.x); acc[1] += a * b2f(u4.y);
                acc[2] += a * b2f(u4.z); acc[3] += a * b2f(u4.w);
            }
        }
    } else {
        // general path (deg > 64): strided stats w/ recompute, chunked agg
        float m[H], sum[H];
#pragma unroll
        for (int j = 0; j < H; j++) m[j] = -3.402823466e38f;
        for (int e = beg + lane; e < end; e += 64) {
            int s = csrc[e];
#pragma unroll
            for (int g = 0; g < H4; g++) {
                float4 as = *(const float4*)(al_s + (size_t)s * H + g * 4);
                m[g * 4 + 0] = fmaxf(m[g * 4 + 0], lrelu(as.x + ad[g * 4 + 0]));
                m[g * 4 + 1] = fmaxf(m[g * 4 + 1], lrelu(as.y + ad[g * 4 + 1]));
                m[g * 4 + 2] = fmaxf(m[g * 4 + 2], lrelu(as.z + ad[g * 4 + 2]));
                m[g * 4 + 3] = fmaxf(m[g * 4 + 3], lrelu(as.w + ad[g * 4 + 3]));
            }
        }
#pragma unroll
        for (int off = 32; off >= 1; off >>= 1)
#pragma unroll
            for (int j = 0; j < H; j++) m[j] = fmaxf(m[j], __shfl_xor(m[j], off));
#pragma unroll
        for (int j = 0; j < H; j++) sum[j] = 0.f;
        for (int e = beg + lane; e < end; e += 64) {
            int s = csrc[e];
#pragma unroll
            for (int g = 0; g < H4; g++) {
                float4 as = *(const float4*)(al_s + (size_t)s * H + g * 4);
                sum[g * 4 + 0] += __expf(lrelu(as.x + ad[g * 4 + 0]) - m[g * 4 + 0]);
                sum[g * 4 + 1] += __expf(lrelu(as.y + ad[g * 4 + 1]) - m[g * 4 + 1]);
                sum[g * 4 + 2] += __expf(lrelu(as.z + ad[g * 4 + 2]) - m[g * 4 + 2]);
                sum[g * 4 + 3] += __expf(lrelu(as.w + ad[g * 4 + 3]) - m[g * 4 + 3]);
            }
        }
#pragma unroll
        for (int off = 32; off >= 1; off >>= 1)
#pragma unroll
            for (int j = 0; j < H; j++) sum[j] += __shfl_xor(sum[j], off);
        float r[H];
#pragma unroll
        for (int j = 0; j < H; j++) r[j] = 1.0f / (sum[j] + 1e-16f);
        for (int base = beg; base < end; base += 64) {
            int cn = end - base < 64 ? end - base : 64;
            __syncthreads();
            if (lane < cn) {
                int s = csrc[base + lane];
                lds_src[lane] = s;
#pragma unroll
                for (int g = 0; g < H4; g++) {
                    float4 as = *(const float4*)(al_s + (size_t)s * H + g * 4);
                    float4 o;
                    o.x = __expf(lrelu(as.x + ad[g * 4 + 0]) - m[g * 4 + 0]) * r[g * 4 + 0];
                    o.y = __expf(lrelu(as.y + ad[g * 4 + 1]) - m[g * 4 + 1]) * r[g * 4 + 1];
                    o.z = __expf(lrelu(as.z + ad[g * 4 + 2]) - m[g * 4 + 2]) * r[g * 4 + 2];
                    o.w = __expf(lrelu(as.w + ad[g * 4 + 3]) - m[g * 4 + 3]) * r[g * 4 + 3];
                    *(float4*)&lds_alpha[lane * H + g * 4] = o;
                }
            }
            __syncthreads();
            for (int t = 0; t < cn; t++) {
                int s2 = lds_src[t];
                float a = lds_alpha[t * H + hh];
                const unsigned short* p = h + (size_t)s2 * HC + ch;
                if constexpr (V == 8) {
                    short8 uv = *(const short8*)p;
#pragma unroll
                    for (int j = 0; j < 8; j++) acc[j] += a * b2f((unsigned short)uv[j]);
                } else {
                    ushort4 u4 = *(const ushort4*)p;
                    acc[0] += a * b2f(u4.x); acc[1] += a * b2f(u4.y);
                    acc[2] += a * b2f(u4.z); acc[3] += a * b2f(u4.w);
                }
            }
        }
    }

    if constexpr (MODE == 0) {
        unsigned short* out = (unsigned short*)out1v;
        if constexpr (V == 8) {
            short8 o;
#pragma unroll
            for (int j = 0; j < 8; j++)
                o[j] = (short)f2b(fmaxf(acc[j] + bias1[ch + j], 0.f));
            *(short8*)(out + (size_t)n * HC + ch) = o;
        } else {
            ushort4 o;
            o.x = f2b(fmaxf(acc[0] + bias1[ch + 0], 0.f));
            o.y = f2b(fmaxf(acc[1] + bias1[ch + 1], 0.f));
            o.z = f2b(fmaxf(acc[2] + bias1[ch + 2], 0.f));
            o.w = f2b(fmaxf(acc[3] + bias1[ch + 3], 0.f));
            *(ushort4*)(out + (size_t)n * HC + ch) = o;
        }
    } else {
        // MODE 1: HC=256, V=4, 8 heads of 32ch -> mean over heads 0-3 / 4-7
        *(float4*)&sh[ch] = make_float4(acc[0], acc[1], acc[2], acc[3]);
        __syncthreads();
        if (lane < 32) {
            float v1 = (sh[lane] + sh[lane + 32] + sh[lane + 64] + sh[lane + 96]) * 0.25f
                       + bias1[lane];
            float v2 = (sh[lane + 128] + sh[lane + 160] + sh[lane + 192] + sh[lane + 224])
                           * 0.25f + bias2[lane];
            ((float*)out1v)[(size_t)n * 32 + lane] = v1;
            ((float*)out2v)[(size_t)n * 32 + lane] = v2;
        }
    }
}

// ---------------- orchestration ----------------

extern "C" void kernel_launch(void* const* d_in, const int* in_sizes, int n_in,
                              void* d_out, int out_size, void* d_ws, size_t ws_size,
                              hipStream_t stream) {
    (void)n_in; (void)out_size; (void)ws_size;
    const float* x   = (const float*)d_in[0];
    const int*   ei  = (const int*)d_in[1];
    const float* W1  = (const float*)d_in[2];
    const float* as1 = (const float*)d_in[3];
    const float* ad1 = (const float*)d_in[4];
    const float* b1  = (const float*)d_in[5];
    const float* W2  = (const float*)d_in[6];
    const float* as2 = (const float*)d_in[7];
    const float* ad2 = (const float*)d_in[8];
    const float* b2  = (const float*)d_in[9];
    const float* Wm  = (const float*)d_in[10];
    const float* a_sm = (const float*)d_in[11];
    const float* a_dm = (const float*)d_in[12];
    const float* bm  = (const float*)d_in[13];
    const float* Wl  = (const float*)d_in[14];
    const float* a_sl = (const float*)d_in[15];
    const float* a_dl = (const float*)d_in[16];
    const float* bl  = (const float*)d_in[17];
    float* outp = (float*)d_out;

    const int N  = in_sizes[0] / 256;   // 30000
    const int E  = in_sizes[1] / 2;     // 480000
    const int ET = E + N;               // with self loops
    const int gM = (N + 127) / 128;     // 235
    const int Mp = gM * 128;            // 30080

    auto align_up = [](size_t v) { return (v + 255) & ~(size_t)255; };
    char* w = (char*)d_ws;
    int* row_ptr = (int*)w;  w += align_up((size_t)(N + 1) * 4);
    int* cnt     = (int*)w;  w += align_up((size_t)N * 4);
    int* csrc    = (int*)w;  w += align_up((size_t)ET * 4);
    float* al_s  = (float*)w; w += align_up((size_t)N * 8 * 4);
    float* al_d  = (float*)w; w += align_up((size_t)N * 8 * 4);
    unsigned short* xb   = (unsigned short*)w; w += align_up((size_t)Mp * 256 * 2);
    unsigned short* W1t  = (unsigned short*)w; w += align_up((size_t)256 * 256 * 2);
    unsigned short* W2t  = (unsigned short*)w; w += align_up((size_t)512 * 256 * 2);
    unsigned short* WmlT = (unsigned short*)w; w += align_up((size_t)256 * 512 * 2);
    unsigned short* bufH = (unsigned short*)w; w += align_up((size_t)N * 512 * 2);
    unsigned short* bufO = (unsigned short*)w; w += align_up((size_t)Mp * 512 * 2);

    // ---- CSR build ----
    int gzE = (ET + 255) / 256;
    hipMemsetAsync(cnt, 0, (size_t)N * 4, stream);
    count_edges_kernel<<<gzE, 256, 0, stream>>>(ei, E, N, cnt);
    scan_kernel<<<1, 1024, 0, stream>>>(cnt, row_ptr, N);   // also re-zeroes cnt
    scatter_edges_kernel<<<gzE, 256, 0, stream>>>(ei, E, N, row_ptr, cnt, csrc);

    // ---- dtype prep ----
    f32_to_bf16_pad4_kernel<<<((Mp * 256 / 4) + 255) / 256, 256, 0, stream>>>(
        x, xb, N, 256, Mp);
    transpose_all_kernel<<<(393216 + 255) / 256, 256, 0, stream>>>(
        W1, W2, Wm, Wl, W1t, W2t, WmlT);

    // ---- Layer 1: GAT(256 -> 4x64, concat) + ReLU ----
    gemm_bf16_kernel<<<dim3(2, gM), 256, 0, stream>>>(xb, W1t, bufH, N, 256, 256);
    al_kernel<<<(N * 4 + 3) / 4, 256, 0, stream>>>(bufH, as1, ad1, as1, ad1,
                                                   al_s, al_d, N * 4, 256, 64, 4);
    gat_fused_kernel<1, 4, 0><<<N, 64, 0, stream>>>(
        row_ptr, csrc, al_s, al_d, bufH, b1, nullptr, bufO, nullptr, 256, 64);

    // ---- Layer 2: GAT(256 -> 4x128, concat) + ReLU ----
    gemm_bf16_kernel<<<dim3(4, gM), 256, 0, stream>>>(bufO, W2t, bufH, N, 256, 512);
    al_kernel<<<(N * 4 + 3) / 4, 256, 0, stream>>>(bufH, as2, ad2, as2, ad2,
                                                   al_s, al_d, N * 4, 512, 128, 4);
    gat_fused_kernel<1, 8, 0><<<N, 64, 0, stream>>>(
        row_ptr, csrc, al_s, al_d, bufH, b2, nullptr, bufO, nullptr, 512, 128);

    // ---- Layers 3+4 batched: GAT(512 -> 8x32, mean per 4-head group) ----
    gemm_bf16_kernel<<<dim3(2, gM), 256, 0, stream>>>(bufO, WmlT, bufH, N, 512, 256);
    al_kernel<<<(N * 8 + 7) / 8, 256, 0, stream>>>(bufH, a_sm, a_dm, a_sl, a_dl,
                                                   al_s, al_d, N * 8, 256, 32, 8);
    gat_fused_kernel<2, 4, 1><<<N, 64, 0, stream>>>(
        row_ptr, csrc, al_s, al_d, bufH, bm, bl, outp, outp + (size_t)N * 32, 256, 32);
}